// Round 7
// baseline (384.320 us; speedup 1.0000x reference)
//
#include <hip/hip_runtime.h>

typedef unsigned short u16;
typedef unsigned int u32;
typedef unsigned long long u64;
typedef short bf16x8 __attribute__((ext_vector_type(8)));
typedef float f32x4 __attribute__((ext_vector_type(4)));
typedef u32 u32x4 __attribute__((ext_vector_type(4)));

__device__ __forceinline__ float b2f(u16 u) {
    return __uint_as_float(((u32)u) << 16);
}
__device__ __forceinline__ u16 f2b(float f) {  // RNE
    u32 u = __float_as_uint(f);
    u32 r = u + 0x7fffu + ((u >> 16) & 1u);
    return (u16)(r >> 16);
}
__device__ __forceinline__ f32x4 mfma16(bf16x8 a, bf16x8 b, f32x4 c) {
    return __builtin_amdgcn_mfma_f32_16x16x32_bf16(a, b, c, 0, 0, 0);
}

// ---------------------------------------------------------------------------
// prep: weights. seg -> W^T[n][k] row-major split bf16 (hi, lo planes).
// seg_bf -> MFMA B-fragment order: [tile][ks][lane][8]. seg_uv -> stacked
// [(Wa1-Wa2)^T ; Wa2^T]. R6: final segment builds pos4[m] = {x,y,z, sum(q^2)}
// with the EXACT __fmul_rn/__fadd_rn sequence knn used in-loop (bit-same).
// ---------------------------------------------------------------------------
template<int NP, int KP, int R, int C>
__device__ __forceinline__ bool seg(int t, int base, const float* src, u16* dst) {
    int r = t - base;
    if (r < 0) return true;
    constexpr int RNG = NP * KP;
    if (r >= RNG) return false;
    int n = r / KP, k = r - n * KP;
    float v = (k < R && n < C) ? src[k * C + n] : 0.f;
    u16 hi = f2b(v);
    dst[r] = hi;
    dst[RNG + r] = f2b(v - b2f(hi));
    return true;
}
template<int NP, int KP, int R, int C>
__device__ __forceinline__ bool seg_bf(int t, int base, const float* src, u16* dst) {
    int r = t - base;
    if (r < 0) return true;
    constexpr int RNG = NP * KP;
    if (r >= RNG) return false;
    constexpr int KC = KP / 32;
    int j = r & 7, s = r >> 3;
    int lanei = s & 63;
    int ks = (s >> 6) % KC, tile = (s >> 6) / KC;
    int n = tile * 16 + (lanei & 15);
    int k = ks * 32 + (lanei >> 4) * 8 + j;
    float v = (k < R && n < C) ? src[k * C + n] : 0.f;
    u16 hi = f2b(v);
    dst[r] = hi;
    dst[RNG + r] = f2b(v - b2f(hi));
    return true;
}
template<int CMID, int CIN, int KP>
__device__ __forceinline__ bool seg_uv(int t, int base, const float* wa, u16* dst) {
    int r = t - base;
    if (r < 0) return true;
    constexpr int RNG = 2 * CMID * KP;
    if (r >= RNG) return false;
    int n = r / KP, k = r - n * KP;
    float v = 0.f;
    if (k < CIN) {
        if (n < CMID) v = wa[k * CMID + n] - wa[(CIN + k) * CMID + n];
        else          v = wa[(CIN + k) * CMID + (n - CMID)];
    }
    u16 hi = f2b(v);
    dst[r] = hi;
    dst[RNG + r] = f2b(v - b2f(hi));
    return true;
}

__global__ __launch_bounds__(256) void prep_weights(
    const float* w1a, const float* w1b, const float* w2a, const float* w2b,
    const float* w3a, const float* w3b, const float* wf1, const float* wf2,
    const float* wf3, const float* pos,
    u16* t1uv, u16* t2uv, u16* t3uv, u16* t1b, u16* t2b, u16* t3b,
    u16* tf1, u16* tf2, u16* tf3, float4* pos4)
{
    int t = blockIdx.x * 256 + threadIdx.x;
    if (seg_uv< 64,   3,  32>(t,      0, w1a, t1uv)) return;
    if (seg_uv< 64,  64,  64>(t,   4096, w2a, t2uv)) return;
    if (seg_uv<128, 128, 128>(t,  12288, w3a, t3uv)) return;
    if (seg_bf< 64,  64,  64,  64>(t,  45056, w1b, t1b)) return;
    if (seg_bf<128,  64,  64, 128>(t,  49152, w2b, t2b)) return;
    if (seg_bf<512, 128, 128, 512>(t,  57344, w3b, t3b)) return;
    if (seg<512, 704, 704, 512>(t, 122880, wf1, tf1)) return;
    if (seg<256, 512, 512, 256>(t, 483328, wf2, tf2)) return;
    if (seg< 16, 256, 256,  12>(t, 614400, wf3, tf3)) return;
    int r = t - 618496;
    if (r >= 0 && r < 16384) {
        const float* q = pos + (size_t)r * 3;
        float q0 = q[0], q1 = q[1], q2 = q[2];
        float sqm = __fadd_rn(__fadd_rn(__fmul_rn(q0, q0), __fmul_rn(q1, q1)),
                              __fmul_rn(q2, q2));
        float4 v; v.x = q0; v.y = q1; v.z = q2; v.w = sqm;
        pos4[r] = v;
    }
}

// ---------------------------------------------------------------------------
// kNN: one WAVE per point. Key = 2^52 + ((orderable(d2) << 11) | idx) built
// via BIT-PACKING (no int->f64 cvt): same-exponent positive doubles compare
// monotonically in the 43-bit integer key, so fmin/fmax are exact 1-instr
// lexicographic (d2, idx) comparisons. d2 arithmetic bit-identical to the
// proven kernel: sq terms precomputed in prep with the SAME rounding sequence.
//  R6: pos read as ONE coalesced float4 {x,y,z,sq} per point (was 3 scalar
//  loads + 5 VALU recomputing sq per pair).
//  Phase 1: T = 32nd-smallest of the 64 lane-minima (bitonic across lanes);
//    lane-min is a 5-deep pairwise tree (R5).
//  Phase 2: ballot-compact keys <= T into LDS (cap 256, pad 1e300).
//  R2: selection = ONE 256-element bitonic sort (4 regs/lane, blocked map
//  i = lane*4+r). First 32 sorted elements = lanes 0..7, stored as int4.
//  Gate -> fallback (exact).
// ---------------------------------------------------------------------------
__device__ __forceinline__ void bitonic256(double v[4], int lane) {
#pragma unroll
    for (int k = 2; k <= 256; k <<= 1) {
#pragma unroll
        for (int j = k >> 1; j > 0; j >>= 1) {
            if (j >= 4) {
                int lj = j >> 2;
                bool upLane = ((lane & (k >> 2)) == 0);   // k>=8 here; r&k==0
                bool lowLane = ((lane & lj) == 0);
                bool keepMin = (upLane == lowLane);
#pragma unroll
                for (int r = 0; r < 4; ++r) {
                    double o = __shfl_xor(v[r], lj);
                    double mn = fmin(v[r], o), mx = fmax(v[r], o);
                    v[r] = keepMin ? mn : mx;
                }
            } else {
#pragma unroll
                for (int r = 0; r < 4; ++r) {
                    if ((r & j) == 0) {
                        int r2 = r | j;
                        bool up = (((lane * 4 + r) & k) == 0);
                        double mn = fmin(v[r], v[r2]), mx = fmax(v[r], v[r2]);
                        v[r] = up ? mn : mx;
                        v[r2] = up ? mx : mn;
                    }
                }
            }
        }
    }
}

__global__ __launch_bounds__(256) void knn_kernel(const float4* __restrict__ pos4,
                                                  int* __restrict__ idxout)
{
    int tid = threadIdx.x, lane = tid & 63, wv = tid >> 6;
    int p = blockIdx.x * 4 + wv;
    int b = p >> 11, n = p & 2047;
    __shared__ double cand[4][256];
    const float4* pb4 = pos4 + (size_t)b * 2048;
    float4 pn = pb4[n];
    float pn0 = pn.x, pn1 = pn.y, pn2 = pn.z, sqn = pn.w;
    double kd[32];
#pragma unroll
    for (int j = 0; j < 32; ++j) {
        int m = lane + j * 64;
        float4 qm = pb4[m];
        float dot = __fadd_rn(__fadd_rn(__fmul_rn(pn0, qm.x), __fmul_rn(pn1, qm.y)),
                              __fmul_rn(pn2, qm.z));
        float d2 = __fadd_rn(__fsub_rn(sqn, __fmul_rn(2.0f, dot)), qm.w);
        u32 u = __float_as_uint(d2);
        u = (u & 0x80000000u) ? ~u : (u | 0x80000000u);  // orderable
        // key64 = (u << 11) | m  (43 bits); embed as 2^52 + key64 bit-exactly
        u32 lo = (u << 11) | (u32)m;
        u32 hi = 0x43300000u | (u >> 21);
        kd[j] = __hiloint2double((int)hi, (int)lo);
    }

    // Phase 1: lane-minima (pairwise tree, 5 deep, 16-way ILP at the top),
    // bitonic sort across 64 lanes, T = 32nd smallest.
    double tmin[16];
#pragma unroll
    for (int j = 0; j < 16; ++j) tmin[j] = fmin(kd[j], kd[j + 16]);
#pragma unroll
    for (int j = 0; j < 8; ++j) tmin[j] = fmin(tmin[j], tmin[j + 8]);
#pragma unroll
    for (int j = 0; j < 4; ++j) tmin[j] = fmin(tmin[j], tmin[j + 4]);
    double lmin = fmin(fmin(tmin[0], tmin[2]), fmin(tmin[1], tmin[3]));
    double v = lmin;
#pragma unroll
    for (int k = 2; k <= 64; k <<= 1) {
#pragma unroll
        for (int j2 = k >> 1; j2 > 0; j2 >>= 1) {
            double o = __shfl_xor(v, j2);
            bool up = ((lane & k) == 0);
            bool low = ((lane & j2) == 0);
            double mn = fmin(v, o), mx = fmax(v, o);
            v = (up == low) ? mn : mx;
        }
    }
    double T = __shfl(v, 31);

    // Phase 2: pad + ballot-compact keys <= T into LDS.
#pragma unroll
    for (int s = 0; s < 4; ++s) cand[wv][lane + s * 64] = 1e300;
    int base = 0;
#pragma unroll
    for (int j = 0; j < 32; ++j) {
        bool pred = (kd[j] <= T);
        u64 bal = __ballot(pred);
        int prefix = (int)__popcll(bal & ((1ull << lane) - 1ull));
        int slot = base + prefix;
        if (pred && slot < 256) cand[wv][slot] = kd[j];
        base += (int)__popcll(bal);
    }

    if (base <= 256) {   // base >= 32 guaranteed (32 lane-minima <= T)
        double kc[4];
#pragma unroll
        for (int j = 0; j < 4; ++j) kc[j] = cand[wv][lane * 4 + j];
        bitonic256(kc, lane);
        if (lane < 8) {
            int4 w;
            w.x = __double2loint(kc[0]) & 2047;
            w.y = __double2loint(kc[1]) & 2047;
            w.z = __double2loint(kc[2]) & 2047;
            w.w = __double2loint(kc[3]) & 2047;
            *(int4*)&idxout[(size_t)p * 32 + lane * 4] = w;
        }
    } else {
        // Fallback: exact full-register selection (R9 path).
        double last = -1.0;
        for (int it = 0; it < 32; ++it) {
            double lm0 = 1e300, lm1 = 1e300;
#pragma unroll
            for (int j = 0; j < 32; j += 2) {
                double t0 = kd[j], t1 = kd[j + 1];
                lm0 = fmin(lm0, (t0 > last) ? t0 : 1e300);
                lm1 = fmin(lm1, (t1 > last) ? t1 : 1e300);
            }
            double lm = fmin(lm0, lm1);
#pragma unroll
            for (int off = 32; off; off >>= 1)
                lm = fmin(lm, __shfl_xor(lm, off));
            if (lane == 0) idxout[(size_t)p * 32 + it] = __double2loint(lm) & 2047;
            last = lm;
        }
    }
}

// ---------------------------------------------------------------------------
// UV GEMM: U[n][c] = x@(Wa1-Wa2)+ba  (f32, exact, read once per point);
//          V[n][c] = x@Wa2           (bf16, gathered 32x -> half traffic).
// A f32 -> split LDS, 3-term MFMA vs split weights (defines U/V precision).
// ---------------------------------------------------------------------------
template<int K, int KP, int N2>
__global__ __launch_bounds__(256) void uv_gemm(
    const float* __restrict__ xin, const u16* __restrict__ wT,
    const float* __restrict__ ba, float* __restrict__ Uf, u16* __restrict__ Vb)
{
    constexpr int SA = KP + 8;
    constexpr int WSZ = N2 * KP;
    constexpr int CMID = N2 / 2;
    __shared__ __align__(16) u16 AsH[32 * SA];
    __shared__ __align__(16) u16 AsL[32 * SA];
    int row0 = blockIdx.x * 32;
    int tid = threadIdx.x, lane = tid & 63, wv = tid >> 6, ln = lane & 15, q = lane >> 4;

    for (int e = tid; e < 32 * (KP / 8); e += 256) {
        int r = e / (KP / 8), c0 = (e % (KP / 8)) * 8;
        bf16x8 hv, lv;
#pragma unroll
        for (int jj = 0; jj < 8; ++jj) {
            int c = c0 + jj;
            float v = (c < K) ? xin[(size_t)(row0 + r) * K + c] : 0.f;
            u16 hi = f2b(v);
            hv[jj] = hi;
            lv[jj] = f2b(v - b2f(hi));
        }
        *(bf16x8*)&AsH[r * SA + c0] = hv;
        *(bf16x8*)&AsL[r * SA + c0] = lv;
    }
    __syncthreads();

    constexpr int NT = N2 / 64;
    f32x4 acc[2][NT] = {};
    const int wbase = wv * (N2 / 4);
#pragma unroll
    for (int ks = 0; ks < KP / 32; ++ks) {
        bf16x8 a0h = *(const bf16x8*)&AsH[(ln) * SA + ks * 32 + q * 8];
        bf16x8 a1h = *(const bf16x8*)&AsH[(16 + ln) * SA + ks * 32 + q * 8];
        bf16x8 a0l = *(const bf16x8*)&AsL[(ln) * SA + ks * 32 + q * 8];
        bf16x8 a1l = *(const bf16x8*)&AsL[(16 + ln) * SA + ks * 32 + q * 8];
#pragma unroll
        for (int nt = 0; nt < NT; ++nt) {
            size_t wi = (size_t)(wbase + nt * 16 + ln) * KP + ks * 32 + q * 8;
            bf16x8 bh = *(const bf16x8*)&wT[wi];
            bf16x8 bl = *(const bf16x8*)&wT[WSZ + wi];
            acc[0][nt] = mfma16(a0h, bh, acc[0][nt]);
            acc[0][nt] = mfma16(a0h, bl, acc[0][nt]);
            acc[0][nt] = mfma16(a0l, bh, acc[0][nt]);
            acc[1][nt] = mfma16(a1h, bh, acc[1][nt]);
            acc[1][nt] = mfma16(a1h, bl, acc[1][nt]);
            acc[1][nt] = mfma16(a1l, bh, acc[1][nt]);
        }
    }
#pragma unroll
    for (int nt = 0; nt < NT; ++nt) {
        int col = wbase + nt * 16 + ln;
#pragma unroll
        for (int mt = 0; mt < 2; ++mt)
#pragma unroll
            for (int r = 0; r < 4; ++r) {
                size_t row = (size_t)(row0 + mt * 16 + q * 4 + r);
                if (col < CMID)
                    Uf[row * CMID + col] = acc[mt][nt][r] + ba[col];
                else
                    Vb[row * CMID + (col - CMID)] = f2b(acc[mt][nt][r]);
            }
    }
}

// ---------------------------------------------------------------------------
// Edge pool — R2-PROVEN config (90.0us R6-measured; R16 laws: PTS=2, (256,4),
// NTP<=2, 1-term Wb). R3/R4 register-hoist variants REFUTED: allocator pins
// 64 VGPR under (256,4) and spills (R3: +10MB scratch) or rematerializes +
// loses occupancy under (256,3) (R4: 39%->30%). Do not re-attempt A-frag
// register residency with this structure.
// R1: ks loop unrolled + 1-deep weight prefetch (bh/bhn); conversion
// loop unrolled. Tripwire: WRITE_SIZE ~= output, VGPR=64, occ ~39%.
// ---------------------------------------------------------------------------
template<int CMID, int COUT, bool OUTB, int PTS, int NTP>
__global__ __launch_bounds__(256, 4) void edge_pool(
    const float* __restrict__ Uf, const u16* __restrict__ Vb,
    const int* __restrict__ idx,
    const u16* __restrict__ wbT, const float* __restrict__ bb,
    void* __restrict__ outp)
{
    constexpr int KC = CMID / 32;
    constexpr int C8 = CMID / 8;
    constexpr int NTW = COUT / 64;
    constexpr int CITER = PTS * 32 * C8 / 256;  // exact (divisible)
    __shared__ __align__(16) u16 hfrag[PTS * 2 * KC * 512];
    __shared__ int nbr[PTS * 32];

    int tid = threadIdx.x, lane = tid & 63, wv = tid >> 6, ln = lane & 15, q = lane >> 4;
    int p0 = blockIdx.x * PTS;

    if (tid < PTS * 32) {
        int pt = tid >> 5, kk = tid & 31;
        int p = p0 + pt;
        nbr[tid] = ((p >> 11) << 11) + (idx[(size_t)p * 32 + kk] & 2047);
    }
    __syncthreads();

    // build h in swizzled fragment order (packed conversion), unrolled so the
    // per-iteration gather/U loads issue back-to-back and pipeline
#pragma unroll
    for (int e0 = 0; e0 < CITER; ++e0) {
        int e = tid + e0 * 256;
        int pt = e / (32 * C8), rem = e % (32 * C8), r = rem / C8, c8 = rem % C8;
        const float* U = &Uf[(size_t)(p0 + pt) * CMID + c8 * 8];
        bf16x8 vb = *(const bf16x8*)&Vb[(size_t)nbr[pt * 32 + r] * CMID + c8 * 8];
        u32x4 hq;
#pragma unroll
        for (int jj = 0; jj < 4; ++jj) {
            float f0 = U[2 * jj]     + b2f((u16)vb[2 * jj]);
            float f1 = U[2 * jj + 1] + b2f((u16)vb[2 * jj + 1]);
            f0 = f0 >= 0.f ? f0 : 0.2f * f0;
            f1 = f1 >= 0.f ? f1 : 0.2f * f1;
            u32 a = __float_as_uint(f0) + 0x8000u;
            u32 b = __float_as_uint(f1) + 0x8000u;
            hq[jj] = __builtin_amdgcn_perm(b, a, 0x07060302u);  // hi16(f1)<<16|hi16(f0)
        }
        int mt = r >> 4, lnr = r & 15, ks = c8 >> 2, qq = c8 & 3;
        int slot = qq * 16 + (lnr ^ ((ks << 2) | qq));
        *(u32x4*)&hfrag[(((pt * 2 + mt) * KC + ks) * 64 + slot) * 8] = hq;
    }
    __syncthreads();

    for (int ng = 0; ng < NTW; ng += NTP) {
        f32x4 acc[PTS][2][NTP] = {};  // [pt][mt][nt]
        bf16x8 bh[NTP];
#pragma unroll
        for (int nt = 0; nt < NTP; ++nt) {
            size_t wi = ((size_t)((wv * NTW + ng + nt) * KC + 0) * 64 + lane) * 8;
            bh[nt] = *(const bf16x8*)&wbT[wi];
        }
#pragma unroll
        for (int ks = 0; ks < KC; ++ks) {
            bf16x8 bhn[NTP];
            if (ks + 1 < KC) {
#pragma unroll
                for (int nt = 0; nt < NTP; ++nt) {
                    size_t wi = ((size_t)((wv * NTW + ng + nt) * KC + (ks + 1)) * 64 + lane) * 8;
                    bhn[nt] = *(const bf16x8*)&wbT[wi];
                }
            }
            int slot = q * 16 + (ln ^ ((ks << 2) | q));
#pragma unroll
            for (int pt = 0; pt < PTS; ++pt)
#pragma unroll
                for (int mt = 0; mt < 2; ++mt) {
                    bf16x8 a = *(const bf16x8*)
                        &hfrag[(((pt * 2 + mt) * KC + ks) * 64 + slot) * 8];
#pragma unroll
                    for (int nt = 0; nt < NTP; ++nt)
                        acc[pt][mt][nt] = mfma16(a, bh[nt], acc[pt][mt][nt]);
                }
            if (ks + 1 < KC) {
#pragma unroll
                for (int nt = 0; nt < NTP; ++nt) bh[nt] = bhn[nt];
            }
        }
        // per-point max over 32 rows, bias+lrelu, store (frees accs)
#pragma unroll
        for (int pt = 0; pt < PTS; ++pt)
#pragma unroll
            for (int nt = 0; nt < NTP; ++nt) {
                int col = wv * (COUT / 4) + (ng + nt) * 16 + ln;
                float m = acc[pt][0][nt][0];
#pragma unroll
                for (int r = 1; r < 4; ++r) m = fmaxf(m, acc[pt][0][nt][r]);
#pragma unroll
                for (int r = 0; r < 4; ++r) m = fmaxf(m, acc[pt][1][nt][r]);
                m = fmaxf(m, __shfl_xor(m, 16));
                m = fmaxf(m, __shfl_xor(m, 32));
                if (q == 0) {
                    float v = m + bb[col];
                    v = v >= 0.f ? v : 0.2f * v;
                    if constexpr (OUTB)
                        ((u16*)outp)[(size_t)(p0 + pt) * COUT + col] = f2b(v);
                    else
                        ((float*)outp)[(size_t)(p0 + pt) * COUT + col] = v;
                }
            }
    }
}

// ---------------------------------------------------------------------------
// head1: concat[x1(f32,64)|x2(f32,128)|x3(bf16,512)] (704) -> 512, lrelu,
// out bf16. 32 rows/WG, K tiled 2x352. W hi-plane only (R15/R16 validated);
// A-side split kept for the f32 x1/x2 columns.
// ---------------------------------------------------------------------------
__global__ __launch_bounds__(256) void head1(
    const float* __restrict__ x1, const float* __restrict__ x2,
    const u16* __restrict__ x3,
    const u16* __restrict__ wT, const float* __restrict__ bias,
    u16* __restrict__ out)
{
    constexpr int KD = 704, KT = 352, SA = 360, COUT = 512;
    __shared__ __align__(16) u16 AsH[32 * SA];
    __shared__ __align__(16) u16 AsL[32 * SA];
    int row0 = blockIdx.x * 32;
    int tid = threadIdx.x, lane = tid & 63, wv = tid >> 6, ln = lane & 15, q = lane >> 4;

    f32x4 acc[2][8] = {};
    const int wbase = wv * 128;

    for (int ph = 0; ph < 2; ++ph) {
        if (ph) __syncthreads();
        for (int e = tid; e < 32 * 44; e += 256) {
            int r = e / 44, c8l = e % 44;
            int c = ph * KT + c8l * 8;
            int g = row0 + r;
            int a = r * SA + c8l * 8;
            if (c < 192) {
                const float* src = (c < 64) ? &x1[(size_t)g * 64 + c]
                                            : &x2[(size_t)g * 128 + (c - 64)];
                bf16x8 hv, lv;
#pragma unroll
                for (int jj = 0; jj < 8; ++jj) {
                    float v = src[jj];
                    u16 hi = f2b(v);
                    hv[jj] = hi;
                    lv[jj] = f2b(v - b2f(hi));
                }
                *(bf16x8*)&AsH[a] = hv;
                *(bf16x8*)&AsL[a] = lv;
            } else {
                *(bf16x8*)&AsH[a] = *(const bf16x8*)&x3[(size_t)g * 512 + (c - 192)];
                bf16x8 z = {0, 0, 0, 0, 0, 0, 0, 0};
                *(bf16x8*)&AsL[a] = z;
            }
        }
        __syncthreads();
        for (int ks = 0; ks < 11; ++ks) {
            int gk = ph * 11 + ks;
            bool t3 = (gk < 6);
            bf16x8 a0h = *(const bf16x8*)&AsH[(ln) * SA + ks * 32 + q * 8];
            bf16x8 a1h = *(const bf16x8*)&AsH[(16 + ln) * SA + ks * 32 + q * 8];
            bf16x8 a0l = *(const bf16x8*)&AsL[(ln) * SA + ks * 32 + q * 8];
            bf16x8 a1l = *(const bf16x8*)&AsL[(16 + ln) * SA + ks * 32 + q * 8];
#pragma unroll
            for (int nt = 0; nt < 8; ++nt) {
                size_t wi = (size_t)(wbase + nt * 16 + ln) * KD + gk * 32 + q * 8;
                bf16x8 bh = *(const bf16x8*)&wT[wi];
                acc[0][nt] = mfma16(a0h, bh, acc[0][nt]);
                acc[1][nt] = mfma16(a1h, bh, acc[1][nt]);
                if (t3) {
                    acc[0][nt] = mfma16(a0l, bh, acc[0][nt]);
                    acc[1][nt] = mfma16(a1l, bh, acc[1][nt]);
                }
            }
        }
    }
#pragma unroll
    for (int nt = 0; nt < 8; ++nt) {
        int col = wbase + nt * 16 + ln;
        float bv = bias[col];
#pragma unroll
        for (int mt = 0; mt < 2; ++mt)
#pragma unroll
            for (int r = 0; r < 4; ++r) {
                float v = acc[mt][nt][r] + bv;
                v = v >= 0.f ? v : 0.2f * v;
                out[(size_t)(row0 + mt * 16 + q * 4 + r) * COUT + col] = f2b(v);
            }
    }
}

// ---------------------------------------------------------------------------
// head_bf: A bf16 [16384][K] -> COUT, W hi-plane only, lrelu, out bf16.
// ---------------------------------------------------------------------------
template<int K, int COUT>
__global__ __launch_bounds__(256) void head_bf(
    const u16* __restrict__ A, const u16* __restrict__ wT,
    const float* __restrict__ bias, u16* __restrict__ out)
{
    constexpr int SA = K + 8;
    __shared__ __align__(16) u16 As[32 * SA];
    int row0 = blockIdx.x * 32;
    int tid = threadIdx.x, lane = tid & 63, wv = tid >> 6, ln = lane & 15, q = lane >> 4;

    for (int e = tid; e < 32 * (K / 8); e += 256) {
        int r = e / (K / 8), c0 = (e % (K / 8)) * 8;
        *(bf16x8*)&As[r * SA + c0] = *(const bf16x8*)&A[(size_t)(row0 + r) * K + c0];
    }
    __syncthreads();

    constexpr int NT = COUT / 64;
    f32x4 acc[2][NT] = {};
    const int wbase = wv * (COUT / 4);
    for (int ks = 0; ks < K / 32; ++ks) {
        bf16x8 a0 = *(const bf16x8*)&As[(ln) * SA + ks * 32 + q * 8];
        bf16x8 a1 = *(const bf16x8*)&As[(16 + ln) * SA + ks * 32 + q * 8];
#pragma unroll
        for (int nt = 0; nt < NT; ++nt) {
            size_t wi = (size_t)(wbase + nt * 16 + ln) * K + ks * 32 + q * 8;
            bf16x8 bh = *(const bf16x8*)&wT[wi];
            acc[0][nt] = mfma16(a0, bh, acc[0][nt]);
            acc[1][nt] = mfma16(a1, bh, acc[1][nt]);
        }
    }
#pragma unroll
    for (int nt = 0; nt < NT; ++nt) {
        int col = wbase + nt * 16 + ln;
        float bv = bias[col];
#pragma unroll
        for (int mt = 0; mt < 2; ++mt)
#pragma unroll
            for (int r = 0; r < 4; ++r) {
                float v = acc[mt][nt][r] + bv;
                v = v >= 0.f ? v : 0.2f * v;
                out[(size_t)(row0 + mt * 16 + q * 4 + r) * COUT + col] = f2b(v);
            }
    }
}

// ---------------------------------------------------------------------------
// head3: A bf16 [16384][256] -> 12 (N padded 16), W hi-plane only, out f32.
// ---------------------------------------------------------------------------
__global__ __launch_bounds__(256) void head_gemm3(
    const u16* __restrict__ A, const u16* __restrict__ wT,
    const float* __restrict__ bias, float* __restrict__ out)
{
    int tid = threadIdx.x, lane = tid & 63, wv = tid >> 6, ln = lane & 15, q = lane >> 4;
    int row0 = (blockIdx.x * 4 + wv) * 32;
    f32x4 acc[2] = {};
#pragma unroll
    for (int ks = 0; ks < 8; ++ks) {
        bf16x8 a0 = *(const bf16x8*)&A[(size_t)(row0 + ln) * 256 + ks * 32 + q * 8];
        bf16x8 a1 = *(const bf16x8*)&A[(size_t)(row0 + 16 + ln) * 256 + ks * 32 + q * 8];
        size_t wi = (size_t)ln * 256 + ks * 32 + q * 8;
        bf16x8 bh = *(const bf16x8*)&wT[wi];
        acc[0] = mfma16(a0, bh, acc[0]);
        acc[1] = mfma16(a1, bh, acc[1]);
    }
    if (ln < 12) {
        float bv = bias[ln];
#pragma unroll
        for (int mt = 0; mt < 2; ++mt)
#pragma unroll
            for (int r = 0; r < 4; ++r)
                out[(size_t)(row0 + mt * 16 + q * 4 + r) * 12 + ln] = acc[mt][r] + bv;
    }
}

// ---------------------------------------------------------------------------
// Workspace (peak 50,708,480 B = 48.4 MB):
//   [0,        2473984)  split weights
//   [2473984,  4571136)  idxb
//   [4571136,  8765440)  x1 f32      (pos4 256KB overlays head of this region
//                        during prep+knn; x1 written after knn -> safe.
//                        dead after head1; h2 bf16 overlays)
//   [8765440, 17154048)  x2 f32      (dead after head1)
//   [17154048,33931264)  Uf f32 (<=8MB) @ +0, Vb bf16 (<=4MB) @ +8MB;
//                        h1 bf16 (16MB) overlays whole region after edge3
//   [33931264,50708480)  x3 bf16
// ---------------------------------------------------------------------------
extern "C" void kernel_launch(void* const* d_in, const int* in_sizes, int n_in,
                              void* d_out, int out_size, void* d_ws, size_t ws_size,
                              hipStream_t stream)
{
    (void)in_sizes; (void)n_in; (void)out_size; (void)ws_size;
    const float* x   = (const float*)d_in[0];
    const float* pos = (const float*)d_in[1];
    const float* w1a = (const float*)d_in[2];  const float* b1a = (const float*)d_in[3];
    const float* w1b = (const float*)d_in[4];  const float* b1b = (const float*)d_in[5];
    const float* w2a = (const float*)d_in[6];  const float* b2a = (const float*)d_in[7];
    const float* w2b = (const float*)d_in[8];  const float* b2b = (const float*)d_in[9];
    const float* w3a = (const float*)d_in[10]; const float* b3a = (const float*)d_in[11];
    const float* w3b = (const float*)d_in[12]; const float* b3b = (const float*)d_in[13];
    const float* wf1 = (const float*)d_in[14]; const float* bf1 = (const float*)d_in[15];
    const float* wf2 = (const float*)d_in[16]; const float* bf2 = (const float*)d_in[17];
    const float* wf3 = (const float*)d_in[18]; const float* bf3 = (const float*)d_in[19];

    char* ws = (char*)d_ws;
    u16* t1uv = (u16*)(ws + 0);
    u16* t2uv = (u16*)(ws + 16384);
    u16* t3uv = (u16*)(ws + 49152);
    u16* t1b  = (u16*)(ws + 180224);
    u16* t2b  = (u16*)(ws + 196608);
    u16* t3b  = (u16*)(ws + 229376);
    u16* tf1  = (u16*)(ws + 491520);
    u16* tf2  = (u16*)(ws + 1933312);
    u16* tf3  = (u16*)(ws + 2457600);
    int*   idxb = (int*)(ws + 2473984);
    float* x1 = (float*)(ws + 4571136);
    float* x2 = (float*)(ws + 8765440);
    float* Uf = (float*)(ws + 17154048);           // <= 8 MB (edge3)
    u16*   Vb = (u16*)(ws + 17154048 + 8388608);   // <= 4 MB (edge3)
    u16*   x3 = (u16*)(ws + 33931264);
    u16*   h1 = (u16*)(ws + 17154048);    // overlays Uf/Vb after edge3
    u16*   h2 = (u16*)(ws + 4571136);     // overlays x1/x2 after head1
    float4* pos4 = (float4*)(ws + 4571136);  // 256KB, dead after knn (x1 overlays)

    prep_weights<<<2480, 256, 0, stream>>>(w1a, w1b, w2a, w2b, w3a, w3b, wf1, wf2, wf3,
                                           pos, t1uv, t2uv, t3uv, t1b, t2b, t3b,
                                           tf1, tf2, tf3, pos4);
    knn_kernel<<<4096, 256, 0, stream>>>(pos4, idxb);
    uv_gemm<  3, 32, 128><<<512, 256, 0, stream>>>(x,  t1uv, b1a, Uf, Vb);
    edge_pool< 64,  64, false, 2, 1><<<8192, 256, 0, stream>>>(Uf, Vb, idxb, t1b, b1b, x1);
    uv_gemm< 64, 64, 128><<<512, 256, 0, stream>>>(x1, t2uv, b2a, Uf, Vb);
    edge_pool< 64, 128, false, 2, 2><<<8192, 256, 0, stream>>>(Uf, Vb, idxb, t2b, b2b, x2);
    uv_gemm<128, 128, 256><<<512, 256, 0, stream>>>(x2, t3uv, b3a, Uf, Vb);
    edge_pool<128, 512, true, 2, 2><<<8192, 256, 0, stream>>>(Uf, Vb, idxb, t3b, b3b, x3);
    head1<<<512, 256, 0, stream>>>(x1, x2, x3, tf1, bf1, h1);
    head_bf<512, 256><<<512, 256, 0, stream>>>(h1, tf2, bf2, h2);
    head_gemm3<<<128, 256, 0, stream>>>(h2, tf3, bf3, (float*)d_out);
}

// Round 8
// 373.277 us; speedup vs baseline: 1.0296x; 1.0296x over previous
//
#include <hip/hip_runtime.h>

typedef unsigned short u16;
typedef unsigned int u32;
typedef unsigned long long u64;
typedef short bf16x8 __attribute__((ext_vector_type(8)));
typedef float f32x4 __attribute__((ext_vector_type(4)));
typedef u32 u32x4 __attribute__((ext_vector_type(4)));

__device__ __forceinline__ float b2f(u16 u) {
    return __uint_as_float(((u32)u) << 16);
}
__device__ __forceinline__ u16 f2b(float f) {  // RNE
    u32 u = __float_as_uint(f);
    u32 r = u + 0x7fffu + ((u >> 16) & 1u);
    return (u16)(r >> 16);
}
__device__ __forceinline__ f32x4 mfma16(bf16x8 a, bf16x8 b, f32x4 c) {
    return __builtin_amdgcn_mfma_f32_16x16x32_bf16(a, b, c, 0, 0, 0);
}

// ---------------------------------------------------------------------------
// prep: weights. seg -> W^T[n][k] row-major split bf16 (hi, lo planes).
// seg_bf -> MFMA B-fragment order: [tile][ks][lane][8]. seg_uv -> stacked
// [(Wa1-Wa2)^T ; Wa2^T]. R6: final segment builds pos4[m] = {x,y,z, sum(q^2)}
// with the EXACT __fmul_rn/__fadd_rn sequence knn used in-loop (bit-same).
// ---------------------------------------------------------------------------
template<int NP, int KP, int R, int C>
__device__ __forceinline__ bool seg(int t, int base, const float* src, u16* dst) {
    int r = t - base;
    if (r < 0) return true;
    constexpr int RNG = NP * KP;
    if (r >= RNG) return false;
    int n = r / KP, k = r - n * KP;
    float v = (k < R && n < C) ? src[k * C + n] : 0.f;
    u16 hi = f2b(v);
    dst[r] = hi;
    dst[RNG + r] = f2b(v - b2f(hi));
    return true;
}
template<int NP, int KP, int R, int C>
__device__ __forceinline__ bool seg_bf(int t, int base, const float* src, u16* dst) {
    int r = t - base;
    if (r < 0) return true;
    constexpr int RNG = NP * KP;
    if (r >= RNG) return false;
    constexpr int KC = KP / 32;
    int j = r & 7, s = r >> 3;
    int lanei = s & 63;
    int ks = (s >> 6) % KC, tile = (s >> 6) / KC;
    int n = tile * 16 + (lanei & 15);
    int k = ks * 32 + (lanei >> 4) * 8 + j;
    float v = (k < R && n < C) ? src[k * C + n] : 0.f;
    u16 hi = f2b(v);
    dst[r] = hi;
    dst[RNG + r] = f2b(v - b2f(hi));
    return true;
}
template<int CMID, int CIN, int KP>
__device__ __forceinline__ bool seg_uv(int t, int base, const float* wa, u16* dst) {
    int r = t - base;
    if (r < 0) return true;
    constexpr int RNG = 2 * CMID * KP;
    if (r >= RNG) return false;
    int n = r / KP, k = r - n * KP;
    float v = 0.f;
    if (k < CIN) {
        if (n < CMID) v = wa[k * CMID + n] - wa[(CIN + k) * CMID + n];
        else          v = wa[(CIN + k) * CMID + (n - CMID)];
    }
    u16 hi = f2b(v);
    dst[r] = hi;
    dst[RNG + r] = f2b(v - b2f(hi));
    return true;
}

__global__ __launch_bounds__(256) void prep_weights(
    const float* w1a, const float* w1b, const float* w2a, const float* w2b,
    const float* w3a, const float* w3b, const float* wf1, const float* wf2,
    const float* wf3, const float* pos,
    u16* t1uv, u16* t2uv, u16* t3uv, u16* t1b, u16* t2b, u16* t3b,
    u16* tf1, u16* tf2, u16* tf3, float4* pos4)
{
    int t = blockIdx.x * 256 + threadIdx.x;
    if (seg_uv< 64,   3,  32>(t,      0, w1a, t1uv)) return;
    if (seg_uv< 64,  64,  64>(t,   4096, w2a, t2uv)) return;
    if (seg_uv<128, 128, 128>(t,  12288, w3a, t3uv)) return;
    if (seg_bf< 64,  64,  64,  64>(t,  45056, w1b, t1b)) return;
    if (seg_bf<128,  64,  64, 128>(t,  49152, w2b, t2b)) return;
    if (seg_bf<512, 128, 128, 512>(t,  57344, w3b, t3b)) return;
    if (seg<512, 704, 704, 512>(t, 122880, wf1, tf1)) return;
    if (seg<256, 512, 512, 256>(t, 483328, wf2, tf2)) return;
    if (seg< 16, 256, 256,  12>(t, 614400, wf3, tf3)) return;
    int r = t - 618496;
    if (r >= 0 && r < 16384) {
        const float* q = pos + (size_t)r * 3;
        float q0 = q[0], q1 = q[1], q2 = q[2];
        float sqm = __fadd_rn(__fadd_rn(__fmul_rn(q0, q0), __fmul_rn(q1, q1)),
                              __fmul_rn(q2, q2));
        float4 v; v.x = q0; v.y = q1; v.z = q2; v.w = sqm;
        pos4[r] = v;
    }
}

// ---------------------------------------------------------------------------
// kNN: one WAVE per point. Key = 2^52 + ((orderable(d2) << 11) | idx) built
// via BIT-PACKING. fmin/fmax = exact lexicographic (d2, idx) compare.
// R6: pos as coalesced float4 {x,y,z,sq}. Phase 1: T = 32nd-smallest of
// lane-minima (R5 pairwise-tree lane-min + 64-lane bitonic). Phase 2:
// ballot-compact keys <= T into LDS. R2: 256-element register bitonic sort,
// first 32 = lanes 0..7 store int4. Gate -> exact fallback.
// ---------------------------------------------------------------------------
__device__ __forceinline__ void bitonic256(double v[4], int lane) {
#pragma unroll
    for (int k = 2; k <= 256; k <<= 1) {
#pragma unroll
        for (int j = k >> 1; j > 0; j >>= 1) {
            if (j >= 4) {
                int lj = j >> 2;
                bool upLane = ((lane & (k >> 2)) == 0);   // k>=8 here; r&k==0
                bool lowLane = ((lane & lj) == 0);
                bool keepMin = (upLane == lowLane);
#pragma unroll
                for (int r = 0; r < 4; ++r) {
                    double o = __shfl_xor(v[r], lj);
                    double mn = fmin(v[r], o), mx = fmax(v[r], o);
                    v[r] = keepMin ? mn : mx;
                }
            } else {
#pragma unroll
                for (int r = 0; r < 4; ++r) {
                    if ((r & j) == 0) {
                        int r2 = r | j;
                        bool up = (((lane * 4 + r) & k) == 0);
                        double mn = fmin(v[r], v[r2]), mx = fmax(v[r], v[r2]);
                        v[r] = up ? mn : mx;
                        v[r2] = up ? mx : mn;
                    }
                }
            }
        }
    }
}

__global__ __launch_bounds__(256) void knn_kernel(const float4* __restrict__ pos4,
                                                  int* __restrict__ idxout)
{
    int tid = threadIdx.x, lane = tid & 63, wv = tid >> 6;
    int p = blockIdx.x * 4 + wv;
    int b = p >> 11, n = p & 2047;
    __shared__ double cand[4][256];
    const float4* pb4 = pos4 + (size_t)b * 2048;
    float4 pn = pb4[n];
    float pn0 = pn.x, pn1 = pn.y, pn2 = pn.z, sqn = pn.w;
    double kd[32];
#pragma unroll
    for (int j = 0; j < 32; ++j) {
        int m = lane + j * 64;
        float4 qm = pb4[m];
        float dot = __fadd_rn(__fadd_rn(__fmul_rn(pn0, qm.x), __fmul_rn(pn1, qm.y)),
                              __fmul_rn(pn2, qm.z));
        float d2 = __fadd_rn(__fsub_rn(sqn, __fmul_rn(2.0f, dot)), qm.w);
        u32 u = __float_as_uint(d2);
        u = (u & 0x80000000u) ? ~u : (u | 0x80000000u);  // orderable
        u32 lo = (u << 11) | (u32)m;
        u32 hi = 0x43300000u | (u >> 21);
        kd[j] = __hiloint2double((int)hi, (int)lo);
    }

    // Phase 1: lane-minima (pairwise tree), 64-lane bitonic, T = 32nd smallest.
    double tmin[16];
#pragma unroll
    for (int j = 0; j < 16; ++j) tmin[j] = fmin(kd[j], kd[j + 16]);
#pragma unroll
    for (int j = 0; j < 8; ++j) tmin[j] = fmin(tmin[j], tmin[j + 8]);
#pragma unroll
    for (int j = 0; j < 4; ++j) tmin[j] = fmin(tmin[j], tmin[j + 4]);
    double lmin = fmin(fmin(tmin[0], tmin[2]), fmin(tmin[1], tmin[3]));
    double v = lmin;
#pragma unroll
    for (int k = 2; k <= 64; k <<= 1) {
#pragma unroll
        for (int j2 = k >> 1; j2 > 0; j2 >>= 1) {
            double o = __shfl_xor(v, j2);
            bool up = ((lane & k) == 0);
            bool low = ((lane & j2) == 0);
            double mn = fmin(v, o), mx = fmax(v, o);
            v = (up == low) ? mn : mx;
        }
    }
    double T = __shfl(v, 31);

    // Phase 2: pad + ballot-compact keys <= T into LDS.
#pragma unroll
    for (int s = 0; s < 4; ++s) cand[wv][lane + s * 64] = 1e300;
    int base = 0;
#pragma unroll
    for (int j = 0; j < 32; ++j) {
        bool pred = (kd[j] <= T);
        u64 bal = __ballot(pred);
        int prefix = (int)__popcll(bal & ((1ull << lane) - 1ull));
        int slot = base + prefix;
        if (pred && slot < 256) cand[wv][slot] = kd[j];
        base += (int)__popcll(bal);
    }

    if (base <= 256) {   // base >= 32 guaranteed (32 lane-minima <= T)
        double kc[4];
#pragma unroll
        for (int j = 0; j < 4; ++j) kc[j] = cand[wv][lane * 4 + j];
        bitonic256(kc, lane);
        if (lane < 8) {
            int4 w;
            w.x = __double2loint(kc[0]) & 2047;
            w.y = __double2loint(kc[1]) & 2047;
            w.z = __double2loint(kc[2]) & 2047;
            w.w = __double2loint(kc[3]) & 2047;
            *(int4*)&idxout[(size_t)p * 32 + lane * 4] = w;
        }
    } else {
        // Fallback: exact full-register selection (R9 path).
        double last = -1.0;
        for (int it = 0; it < 32; ++it) {
            double lm0 = 1e300, lm1 = 1e300;
#pragma unroll
            for (int j = 0; j < 32; j += 2) {
                double t0 = kd[j], t1 = kd[j + 1];
                lm0 = fmin(lm0, (t0 > last) ? t0 : 1e300);
                lm1 = fmin(lm1, (t1 > last) ? t1 : 1e300);
            }
            double lm = fmin(lm0, lm1);
#pragma unroll
            for (int off = 32; off; off >>= 1)
                lm = fmin(lm, __shfl_xor(lm, off));
            if (lane == 0) idxout[(size_t)p * 32 + it] = __double2loint(lm) & 2047;
            last = lm;
        }
    }
}

// ---------------------------------------------------------------------------
// UV GEMM: U[n][c] = x@(Wa1-Wa2)+ba  (f32, exact, read once per point);
//          V[n][c] = x@Wa2           (bf16, gathered 32x -> half traffic).
// A f32 -> split LDS, 3-term MFMA vs split weights (defines U/V precision).
// ---------------------------------------------------------------------------
template<int K, int KP, int N2>
__global__ __launch_bounds__(256) void uv_gemm(
    const float* __restrict__ xin, const u16* __restrict__ wT,
    const float* __restrict__ ba, float* __restrict__ Uf, u16* __restrict__ Vb)
{
    constexpr int SA = KP + 8;
    constexpr int WSZ = N2 * KP;
    constexpr int CMID = N2 / 2;
    __shared__ __align__(16) u16 AsH[32 * SA];
    __shared__ __align__(16) u16 AsL[32 * SA];
    int row0 = blockIdx.x * 32;
    int tid = threadIdx.x, lane = tid & 63, wv = tid >> 6, ln = lane & 15, q = lane >> 4;

    for (int e = tid; e < 32 * (KP / 8); e += 256) {
        int r = e / (KP / 8), c0 = (e % (KP / 8)) * 8;
        bf16x8 hv, lv;
#pragma unroll
        for (int jj = 0; jj < 8; ++jj) {
            int c = c0 + jj;
            float v = (c < K) ? xin[(size_t)(row0 + r) * K + c] : 0.f;
            u16 hi = f2b(v);
            hv[jj] = hi;
            lv[jj] = f2b(v - b2f(hi));
        }
        *(bf16x8*)&AsH[r * SA + c0] = hv;
        *(bf16x8*)&AsL[r * SA + c0] = lv;
    }
    __syncthreads();

    constexpr int NT = N2 / 64;
    f32x4 acc[2][NT] = {};
    const int wbase = wv * (N2 / 4);
#pragma unroll
    for (int ks = 0; ks < KP / 32; ++ks) {
        bf16x8 a0h = *(const bf16x8*)&AsH[(ln) * SA + ks * 32 + q * 8];
        bf16x8 a1h = *(const bf16x8*)&AsH[(16 + ln) * SA + ks * 32 + q * 8];
        bf16x8 a0l = *(const bf16x8*)&AsL[(ln) * SA + ks * 32 + q * 8];
        bf16x8 a1l = *(const bf16x8*)&AsL[(16 + ln) * SA + ks * 32 + q * 8];
#pragma unroll
        for (int nt = 0; nt < NT; ++nt) {
            size_t wi = (size_t)(wbase + nt * 16 + ln) * KP + ks * 32 + q * 8;
            bf16x8 bh = *(const bf16x8*)&wT[wi];
            bf16x8 bl = *(const bf16x8*)&wT[WSZ + wi];
            acc[0][nt] = mfma16(a0h, bh, acc[0][nt]);
            acc[0][nt] = mfma16(a0h, bl, acc[0][nt]);
            acc[0][nt] = mfma16(a0l, bh, acc[0][nt]);
            acc[1][nt] = mfma16(a1h, bh, acc[1][nt]);
            acc[1][nt] = mfma16(a1h, bl, acc[1][nt]);
            acc[1][nt] = mfma16(a1l, bh, acc[1][nt]);
        }
    }
#pragma unroll
    for (int nt = 0; nt < NT; ++nt) {
        int col = wbase + nt * 16 + ln;
#pragma unroll
        for (int mt = 0; mt < 2; ++mt)
#pragma unroll
            for (int r = 0; r < 4; ++r) {
                size_t row = (size_t)(row0 + mt * 16 + q * 4 + r);
                if (col < CMID)
                    Uf[row * CMID + col] = acc[mt][nt][r] + ba[col];
                else
                    Vb[row * CMID + (col - CMID)] = f2b(acc[mt][nt][r]);
            }
    }
}

// ---------------------------------------------------------------------------
// Edge pool — R2-PROVEN config (90-92us measured; R16 laws: PTS=2, (256,4),
// NTP<=2, 1-term Wb). R3/R4 register-hoist variants REFUTED: allocator pins
// 64 VGPR under (256,4) and spills (R3: +10MB scratch) or rematerializes +
// loses occupancy under (256,3) (R4: 39%->30%). Do not re-attempt A-frag
// register residency with this structure.
// R1: ks loop unrolled + 1-deep weight prefetch (bh/bhn); conversion
// loop unrolled. Tripwire: WRITE_SIZE ~= output, VGPR=64, occ ~39%.
// ---------------------------------------------------------------------------
template<int CMID, int COUT, bool OUTB, int PTS, int NTP>
__global__ __launch_bounds__(256, 4) void edge_pool(
    const float* __restrict__ Uf, const u16* __restrict__ Vb,
    const int* __restrict__ idx,
    const u16* __restrict__ wbT, const float* __restrict__ bb,
    void* __restrict__ outp)
{
    constexpr int KC = CMID / 32;
    constexpr int C8 = CMID / 8;
    constexpr int NTW = COUT / 64;
    constexpr int CITER = PTS * 32 * C8 / 256;  // exact (divisible)
    __shared__ __align__(16) u16 hfrag[PTS * 2 * KC * 512];
    __shared__ int nbr[PTS * 32];

    int tid = threadIdx.x, lane = tid & 63, wv = tid >> 6, ln = lane & 15, q = lane >> 4;
    int p0 = blockIdx.x * PTS;

    if (tid < PTS * 32) {
        int pt = tid >> 5, kk = tid & 31;
        int p = p0 + pt;
        nbr[tid] = ((p >> 11) << 11) + (idx[(size_t)p * 32 + kk] & 2047);
    }
    __syncthreads();

    // build h in swizzled fragment order (packed conversion), unrolled so the
    // per-iteration gather/U loads issue back-to-back and pipeline
#pragma unroll
    for (int e0 = 0; e0 < CITER; ++e0) {
        int e = tid + e0 * 256;
        int pt = e / (32 * C8), rem = e % (32 * C8), r = rem / C8, c8 = rem % C8;
        const float* U = &Uf[(size_t)(p0 + pt) * CMID + c8 * 8];
        bf16x8 vb = *(const bf16x8*)&Vb[(size_t)nbr[pt * 32 + r] * CMID + c8 * 8];
        u32x4 hq;
#pragma unroll
        for (int jj = 0; jj < 4; ++jj) {
            float f0 = U[2 * jj]     + b2f((u16)vb[2 * jj]);
            float f1 = U[2 * jj + 1] + b2f((u16)vb[2 * jj + 1]);
            f0 = f0 >= 0.f ? f0 : 0.2f * f0;
            f1 = f1 >= 0.f ? f1 : 0.2f * f1;
            u32 a = __float_as_uint(f0) + 0x8000u;
            u32 b = __float_as_uint(f1) + 0x8000u;
            hq[jj] = __builtin_amdgcn_perm(b, a, 0x07060302u);  // hi16(f1)<<16|hi16(f0)
        }
        int mt = r >> 4, lnr = r & 15, ks = c8 >> 2, qq = c8 & 3;
        int slot = qq * 16 + (lnr ^ ((ks << 2) | qq));
        *(u32x4*)&hfrag[(((pt * 2 + mt) * KC + ks) * 64 + slot) * 8] = hq;
    }
    __syncthreads();

    for (int ng = 0; ng < NTW; ng += NTP) {
        f32x4 acc[PTS][2][NTP] = {};  // [pt][mt][nt]
        bf16x8 bh[NTP];
#pragma unroll
        for (int nt = 0; nt < NTP; ++nt) {
            size_t wi = ((size_t)((wv * NTW + ng + nt) * KC + 0) * 64 + lane) * 8;
            bh[nt] = *(const bf16x8*)&wbT[wi];
        }
#pragma unroll
        for (int ks = 0; ks < KC; ++ks) {
            bf16x8 bhn[NTP];
            if (ks + 1 < KC) {
#pragma unroll
                for (int nt = 0; nt < NTP; ++nt) {
                    size_t wi = ((size_t)((wv * NTW + ng + nt) * KC + (ks + 1)) * 64 + lane) * 8;
                    bhn[nt] = *(const bf16x8*)&wbT[wi];
                }
            }
            int slot = q * 16 + (ln ^ ((ks << 2) | q));
#pragma unroll
            for (int pt = 0; pt < PTS; ++pt)
#pragma unroll
                for (int mt = 0; mt < 2; ++mt) {
                    bf16x8 a = *(const bf16x8*)
                        &hfrag[(((pt * 2 + mt) * KC + ks) * 64 + slot) * 8];
#pragma unroll
                    for (int nt = 0; nt < NTP; ++nt)
                        acc[pt][mt][nt] = mfma16(a, bh[nt], acc[pt][mt][nt]);
                }
            if (ks + 1 < KC) {
#pragma unroll
                for (int nt = 0; nt < NTP; ++nt) bh[nt] = bhn[nt];
            }
        }
        // per-point max over 32 rows, bias+lrelu, store (frees accs)
#pragma unroll
        for (int pt = 0; pt < PTS; ++pt)
#pragma unroll
            for (int nt = 0; nt < NTP; ++nt) {
                int col = wv * (COUT / 4) + (ng + nt) * 16 + ln;
                float m = acc[pt][0][nt][0];
#pragma unroll
                for (int r = 1; r < 4; ++r) m = fmaxf(m, acc[pt][0][nt][r]);
#pragma unroll
                for (int r = 0; r < 4; ++r) m = fmaxf(m, acc[pt][1][nt][r]);
                m = fmaxf(m, __shfl_xor(m, 16));
                m = fmaxf(m, __shfl_xor(m, 32));
                if (q == 0) {
                    float v = m + bb[col];
                    v = v >= 0.f ? v : 0.2f * v;
                    if constexpr (OUTB)
                        ((u16*)outp)[(size_t)(p0 + pt) * COUT + col] = f2b(v);
                    else
                        ((float*)outp)[(size_t)(p0 + pt) * COUT + col] = v;
                }
            }
    }
}

// ---------------------------------------------------------------------------
// head12 (R7 fusion): stage 1 = head1 (concat 704 -> 512, lrelu) kept
// bit-identical; instead of writing h1 (16MB) to HBM, the 32x512 bf16 tile
// goes to an LDS exchange buffer (overlays AsH/AsL after stage-1 compute,
// 33.3KB <= 46KB) laid out exactly like head_bf's As ([32][520], SA=K+8).
// Stage 2 = head_bf<512,256> body verbatim reading that buffer -> h2 bf16.
// Eliminates 16MB h1 write + 16MB read + head_bf staging + 1 launch.
// h2 values bit-identical (same bf16 inputs, same MFMA order, same epilogue).
// ---------------------------------------------------------------------------
__global__ __launch_bounds__(256) void head12(
    const float* __restrict__ x1, const float* __restrict__ x2,
    const u16* __restrict__ x3,
    const u16* __restrict__ wT1, const float* __restrict__ b1,
    const u16* __restrict__ wT2, const float* __restrict__ b2,
    u16* __restrict__ out2)
{
    constexpr int KD = 704, KT = 352, SA = 360, SB = 520;
    __shared__ __align__(16) u16 lds[2 * 32 * SA];   // 46080 B
    u16* AsH = lds;
    u16* AsL = lds + 32 * SA;
    u16* Bs  = lds;                                  // stage-2 overlay [32][SB]
    int row0 = blockIdx.x * 32;
    int tid = threadIdx.x, lane = tid & 63, wv = tid >> 6, ln = lane & 15, q = lane >> 4;

    f32x4 acc[2][8] = {};
    const int wbase = wv * 128;

    for (int ph = 0; ph < 2; ++ph) {
        if (ph) __syncthreads();
        for (int e = tid; e < 32 * 44; e += 256) {
            int r = e / 44, c8l = e % 44;
            int c = ph * KT + c8l * 8;
            int g = row0 + r;
            int a = r * SA + c8l * 8;
            if (c < 192) {
                const float* src = (c < 64) ? &x1[(size_t)g * 64 + c]
                                            : &x2[(size_t)g * 128 + (c - 64)];
                bf16x8 hv, lv;
#pragma unroll
                for (int jj = 0; jj < 8; ++jj) {
                    float v = src[jj];
                    u16 hi = f2b(v);
                    hv[jj] = hi;
                    lv[jj] = f2b(v - b2f(hi));
                }
                *(bf16x8*)&AsH[a] = hv;
                *(bf16x8*)&AsL[a] = lv;
            } else {
                *(bf16x8*)&AsH[a] = *(const bf16x8*)&x3[(size_t)g * 512 + (c - 192)];
                bf16x8 z = {0, 0, 0, 0, 0, 0, 0, 0};
                *(bf16x8*)&AsL[a] = z;
            }
        }
        __syncthreads();
        for (int ks = 0; ks < 11; ++ks) {
            int gk = ph * 11 + ks;
            bool t3 = (gk < 6);
            bf16x8 a0h = *(const bf16x8*)&AsH[(ln) * SA + ks * 32 + q * 8];
            bf16x8 a1h = *(const bf16x8*)&AsH[(16 + ln) * SA + ks * 32 + q * 8];
            bf16x8 a0l = *(const bf16x8*)&AsL[(ln) * SA + ks * 32 + q * 8];
            bf16x8 a1l = *(const bf16x8*)&AsL[(16 + ln) * SA + ks * 32 + q * 8];
#pragma unroll
            for (int nt = 0; nt < 8; ++nt) {
                size_t wi = (size_t)(wbase + nt * 16 + ln) * KD + gk * 32 + q * 8;
                bf16x8 bh = *(const bf16x8*)&wT1[wi];
                acc[0][nt] = mfma16(a0h, bh, acc[0][nt]);
                acc[1][nt] = mfma16(a1h, bh, acc[1][nt]);
                if (t3) {
                    acc[0][nt] = mfma16(a0l, bh, acc[0][nt]);
                    acc[1][nt] = mfma16(a1l, bh, acc[1][nt]);
                }
            }
        }
    }
    // stage-1 epilogue -> LDS exchange (bit-identical values to old h1)
    __syncthreads();   // all AsH/AsL reads done before overlay
#pragma unroll
    for (int nt = 0; nt < 8; ++nt) {
        int col = wbase + nt * 16 + ln;
        float bv = b1[col];
#pragma unroll
        for (int mt = 0; mt < 2; ++mt)
#pragma unroll
            for (int r = 0; r < 4; ++r) {
                float v = acc[mt][nt][r] + bv;
                v = v >= 0.f ? v : 0.2f * v;
                Bs[(mt * 16 + q * 4 + r) * SB + col] = f2b(v);
            }
    }
    __syncthreads();

    // stage 2: head_bf<512,256> body (verbatim indexing, SA -> SB)
    f32x4 acc2[2][4] = {};
    const int wbase2 = wv * 64;
    for (int ks = 0; ks < 16; ++ks) {
        bf16x8 a0 = *(const bf16x8*)&Bs[(ln) * SB + ks * 32 + q * 8];
        bf16x8 a1 = *(const bf16x8*)&Bs[(16 + ln) * SB + ks * 32 + q * 8];
#pragma unroll
        for (int nt = 0; nt < 4; ++nt) {
            size_t wi = (size_t)(wbase2 + nt * 16 + ln) * 512 + ks * 32 + q * 8;
            bf16x8 bh = *(const bf16x8*)&wT2[wi];
            acc2[0][nt] = mfma16(a0, bh, acc2[0][nt]);
            acc2[1][nt] = mfma16(a1, bh, acc2[1][nt]);
        }
    }
#pragma unroll
    for (int nt = 0; nt < 4; ++nt) {
        int col = wbase2 + nt * 16 + ln;
        float bv = b2[col];
#pragma unroll
        for (int mt = 0; mt < 2; ++mt)
#pragma unroll
            for (int r = 0; r < 4; ++r) {
                float v = acc2[mt][nt][r] + bv;
                v = v >= 0.f ? v : 0.2f * v;
                out2[(size_t)(row0 + mt * 16 + q * 4 + r) * 256 + col] = f2b(v);
            }
    }
}

// ---------------------------------------------------------------------------
// head3: A bf16 [16384][256] -> 12 (N padded 16), W hi-plane only, out f32.
// ---------------------------------------------------------------------------
__global__ __launch_bounds__(256) void head_gemm3(
    const u16* __restrict__ A, const u16* __restrict__ wT,
    const float* __restrict__ bias, float* __restrict__ out)
{
    int tid = threadIdx.x, lane = tid & 63, wv = tid >> 6, ln = lane & 15, q = lane >> 4;
    int row0 = (blockIdx.x * 4 + wv) * 32;
    f32x4 acc[2] = {};
#pragma unroll
    for (int ks = 0; ks < 8; ++ks) {
        bf16x8 a0 = *(const bf16x8*)&A[(size_t)(row0 + ln) * 256 + ks * 32 + q * 8];
        bf16x8 a1 = *(const bf16x8*)&A[(size_t)(row0 + 16 + ln) * 256 + ks * 32 + q * 8];
        size_t wi = (size_t)ln * 256 + ks * 32 + q * 8;
        bf16x8 bh = *(const bf16x8*)&wT[wi];
        acc[0] = mfma16(a0, bh, acc[0]);
        acc[1] = mfma16(a1, bh, acc[1]);
    }
    if (ln < 12) {
        float bv = bias[ln];
#pragma unroll
        for (int mt = 0; mt < 2; ++mt)
#pragma unroll
            for (int r = 0; r < 4; ++r)
                out[(size_t)(row0 + mt * 16 + q * 4 + r) * 12 + ln] = acc[mt][r] + bv;
    }
}

// ---------------------------------------------------------------------------
// Workspace (peak 50,708,480 B = 48.4 MB):
//   [0,        2473984)  split weights
//   [2473984,  4571136)  idxb
//   [4571136,  8765440)  x1 f32      (pos4 256KB overlays head during
//                        prep+knn; x1 written after knn -> safe)
//   [8765440, 17154048)  x2 f32
//   [17154048,33931264)  Uf f32 (<=8MB) @ +0, Vb bf16 (<=4MB) @ +8MB;
//                        h2 bf16 (8MB) overlays after edge3 (R7: h1 gone,
//                        head12 reads x1/x2/x3 and writes h2 here)
//   [33931264,50708480)  x3 bf16
// ---------------------------------------------------------------------------
extern "C" void kernel_launch(void* const* d_in, const int* in_sizes, int n_in,
                              void* d_out, int out_size, void* d_ws, size_t ws_size,
                              hipStream_t stream)
{
    (void)in_sizes; (void)n_in; (void)out_size; (void)ws_size;
    const float* x   = (const float*)d_in[0];
    const float* pos = (const float*)d_in[1];
    const float* w1a = (const float*)d_in[2];  const float* b1a = (const float*)d_in[3];
    const float* w1b = (const float*)d_in[4];  const float* b1b = (const float*)d_in[5];
    const float* w2a = (const float*)d_in[6];  const float* b2a = (const float*)d_in[7];
    const float* w2b = (const float*)d_in[8];  const float* b2b = (const float*)d_in[9];
    const float* w3a = (const float*)d_in[10]; const float* b3a = (const float*)d_in[11];
    const float* w3b = (const float*)d_in[12]; const float* b3b = (const float*)d_in[13];
    const float* wf1 = (const float*)d_in[14]; const float* bf1 = (const float*)d_in[15];
    const float* wf2 = (const float*)d_in[16]; const float* bf2 = (const float*)d_in[17];
    const float* wf3 = (const float*)d_in[18]; const float* bf3 = (const float*)d_in[19];

    char* ws = (char*)d_ws;
    u16* t1uv = (u16*)(ws + 0);
    u16* t2uv = (u16*)(ws + 16384);
    u16* t3uv = (u16*)(ws + 49152);
    u16* t1b  = (u16*)(ws + 180224);
    u16* t2b  = (u16*)(ws + 196608);
    u16* t3b  = (u16*)(ws + 229376);
    u16* tf1  = (u16*)(ws + 491520);
    u16* tf2  = (u16*)(ws + 1933312);
    u16* tf3  = (u16*)(ws + 2457600);
    int*   idxb = (int*)(ws + 2473984);
    float* x1 = (float*)(ws + 4571136);
    float* x2 = (float*)(ws + 8765440);
    float* Uf = (float*)(ws + 17154048);           // <= 8 MB (edge3)
    u16*   Vb = (u16*)(ws + 17154048 + 8388608);   // <= 4 MB (edge3)
    u16*   x3 = (u16*)(ws + 33931264);
    u16*   h2 = (u16*)(ws + 17154048);    // 8MB, overlays Uf/Vb after edge3
    float4* pos4 = (float4*)(ws + 4571136);  // 256KB, dead after knn (x1 overlays)

    prep_weights<<<2480, 256, 0, stream>>>(w1a, w1b, w2a, w2b, w3a, w3b, wf1, wf2, wf3,
                                           pos, t1uv, t2uv, t3uv, t1b, t2b, t3b,
                                           tf1, tf2, tf3, pos4);
    knn_kernel<<<4096, 256, 0, stream>>>(pos4, idxb);
    uv_gemm<  3, 32, 128><<<512, 256, 0, stream>>>(x,  t1uv, b1a, Uf, Vb);
    edge_pool< 64,  64, false, 2, 1><<<8192, 256, 0, stream>>>(Uf, Vb, idxb, t1b, b1b, x1);
    uv_gemm< 64, 64, 128><<<512, 256, 0, stream>>>(x1, t2uv, b2a, Uf, Vb);
    edge_pool< 64, 128, false, 2, 2><<<8192, 256, 0, stream>>>(Uf, Vb, idxb, t2b, b2b, x2);
    uv_gemm<128, 128, 256><<<512, 256, 0, stream>>>(x2, t3uv, b3a, Uf, Vb);
    edge_pool<128, 512, true, 2, 2><<<8192, 256, 0, stream>>>(Uf, Vb, idxb, t3b, b3b, x3);
    head12<<<512, 256, 0, stream>>>(x1, x2, x3, tf1, bf1, tf2, bf2, h2);
    head_gemm3<<<128, 256, 0, stream>>>(h2, tf3, bf3, (float*)d_out);
}

// Round 9
// 371.949 us; speedup vs baseline: 1.0333x; 1.0036x over previous
//
#include <hip/hip_runtime.h>

typedef unsigned short u16;
typedef unsigned int u32;
typedef unsigned long long u64;
typedef short bf16x8 __attribute__((ext_vector_type(8)));
typedef float f32x4 __attribute__((ext_vector_type(4)));
typedef u32 u32x4 __attribute__((ext_vector_type(4)));

__device__ __forceinline__ float b2f(u16 u) {
    return __uint_as_float(((u32)u) << 16);
}
__device__ __forceinline__ u16 f2b(float f) {  // RNE
    u32 u = __float_as_uint(f);
    u32 r = u + 0x7fffu + ((u >> 16) & 1u);
    return (u16)(r >> 16);
}
__device__ __forceinline__ f32x4 mfma16(bf16x8 a, bf16x8 b, f32x4 c) {
    return __builtin_amdgcn_mfma_f32_16x16x32_bf16(a, b, c, 0, 0, 0);
}

// ---------------------------------------------------------------------------
// prep: weights. seg -> W^T[n][k] row-major split bf16 (hi, lo planes).
// seg_bf -> MFMA B-fragment order: [tile][ks][lane][8]. seg_uv -> stacked
// [(Wa1-Wa2)^T ; Wa2^T]. R6: final segment builds pos4[m] = {x,y,z, sum(q^2)}
// with the EXACT __fmul_rn/__fadd_rn sequence knn used in-loop (bit-same).
// ---------------------------------------------------------------------------
template<int NP, int KP, int R, int C>
__device__ __forceinline__ bool seg(int t, int base, const float* src, u16* dst) {
    int r = t - base;
    if (r < 0) return true;
    constexpr int RNG = NP * KP;
    if (r >= RNG) return false;
    int n = r / KP, k = r - n * KP;
    float v = (k < R && n < C) ? src[k * C + n] : 0.f;
    u16 hi = f2b(v);
    dst[r] = hi;
    dst[RNG + r] = f2b(v - b2f(hi));
    return true;
}
template<int NP, int KP, int R, int C>
__device__ __forceinline__ bool seg_bf(int t, int base, const float* src, u16* dst) {
    int r = t - base;
    if (r < 0) return true;
    constexpr int RNG = NP * KP;
    if (r >= RNG) return false;
    constexpr int KC = KP / 32;
    int j = r & 7, s = r >> 3;
    int lanei = s & 63;
    int ks = (s >> 6) % KC, tile = (s >> 6) / KC;
    int n = tile * 16 + (lanei & 15);
    int k = ks * 32 + (lanei >> 4) * 8 + j;
    float v = (k < R && n < C) ? src[k * C + n] : 0.f;
    u16 hi = f2b(v);
    dst[r] = hi;
    dst[RNG + r] = f2b(v - b2f(hi));
    return true;
}
template<int CMID, int CIN, int KP>
__device__ __forceinline__ bool seg_uv(int t, int base, const float* wa, u16* dst) {
    int r = t - base;
    if (r < 0) return true;
    constexpr int RNG = 2 * CMID * KP;
    if (r >= RNG) return false;
    int n = r / KP, k = r - n * KP;
    float v = 0.f;
    if (k < CIN) {
        if (n < CMID) v = wa[k * CMID + n] - wa[(CIN + k) * CMID + n];
        else          v = wa[(CIN + k) * CMID + (n - CMID)];
    }
    u16 hi = f2b(v);
    dst[r] = hi;
    dst[RNG + r] = f2b(v - b2f(hi));
    return true;
}

__global__ __launch_bounds__(256) void prep_weights(
    const float* w1a, const float* w1b, const float* w2a, const float* w2b,
    const float* w3a, const float* w3b, const float* wf1, const float* wf2,
    const float* wf3, const float* pos,
    u16* t1uv, u16* t2uv, u16* t3uv, u16* t1b, u16* t2b, u16* t3b,
    u16* tf1, u16* tf2, u16* tf3, float4* pos4)
{
    int t = blockIdx.x * 256 + threadIdx.x;
    if (seg_uv< 64,   3,  32>(t,      0, w1a, t1uv)) return;
    if (seg_uv< 64,  64,  64>(t,   4096, w2a, t2uv)) return;
    if (seg_uv<128, 128, 128>(t,  12288, w3a, t3uv)) return;
    if (seg_bf< 64,  64,  64,  64>(t,  45056, w1b, t1b)) return;
    if (seg_bf<128,  64,  64, 128>(t,  49152, w2b, t2b)) return;
    if (seg_bf<512, 128, 128, 512>(t,  57344, w3b, t3b)) return;
    if (seg<512, 704, 704, 512>(t, 122880, wf1, tf1)) return;
    if (seg<256, 512, 512, 256>(t, 483328, wf2, tf2)) return;
    if (seg< 16, 256, 256,  12>(t, 614400, wf3, tf3)) return;
    int r = t - 618496;
    if (r >= 0 && r < 16384) {
        const float* q = pos + (size_t)r * 3;
        float q0 = q[0], q1 = q[1], q2 = q[2];
        float sqm = __fadd_rn(__fadd_rn(__fmul_rn(q0, q0), __fmul_rn(q1, q1)),
                              __fmul_rn(q2, q2));
        float4 v; v.x = q0; v.y = q1; v.z = q2; v.w = sqm;
        pos4[r] = v;
    }
}

// ---------------------------------------------------------------------------
// kNN: one WAVE per point. Key = 2^52 + ((orderable(d2) << 11) | idx) built
// via BIT-PACKING. fmin/fmax = exact lexicographic (d2, idx) compare.
// R6: pos as coalesced float4 {x,y,z,sq}. Phase 1: T = 32nd-smallest of
// lane-minima (R5 pairwise-tree lane-min + 64-lane bitonic). Phase 2:
// ballot-compact keys <= T into LDS. R2: 256-element register bitonic sort,
// first 32 = lanes 0..7 store int4. Gate -> exact fallback.
// ---------------------------------------------------------------------------
__device__ __forceinline__ void bitonic256(double v[4], int lane) {
#pragma unroll
    for (int k = 2; k <= 256; k <<= 1) {
#pragma unroll
        for (int j = k >> 1; j > 0; j >>= 1) {
            if (j >= 4) {
                int lj = j >> 2;
                bool upLane = ((lane & (k >> 2)) == 0);   // k>=8 here; r&k==0
                bool lowLane = ((lane & lj) == 0);
                bool keepMin = (upLane == lowLane);
#pragma unroll
                for (int r = 0; r < 4; ++r) {
                    double o = __shfl_xor(v[r], lj);
                    double mn = fmin(v[r], o), mx = fmax(v[r], o);
                    v[r] = keepMin ? mn : mx;
                }
            } else {
#pragma unroll
                for (int r = 0; r < 4; ++r) {
                    if ((r & j) == 0) {
                        int r2 = r | j;
                        bool up = (((lane * 4 + r) & k) == 0);
                        double mn = fmin(v[r], v[r2]), mx = fmax(v[r], v[r2]);
                        v[r] = up ? mn : mx;
                        v[r2] = up ? mx : mn;
                    }
                }
            }
        }
    }
}

__global__ __launch_bounds__(256) void knn_kernel(const float4* __restrict__ pos4,
                                                  int* __restrict__ idxout)
{
    int tid = threadIdx.x, lane = tid & 63, wv = tid >> 6;
    int p = blockIdx.x * 4 + wv;
    int b = p >> 11, n = p & 2047;
    __shared__ double cand[4][256];
    const float4* pb4 = pos4 + (size_t)b * 2048;
    float4 pn = pb4[n];
    float pn0 = pn.x, pn1 = pn.y, pn2 = pn.z, sqn = pn.w;
    double kd[32];
#pragma unroll
    for (int j = 0; j < 32; ++j) {
        int m = lane + j * 64;
        float4 qm = pb4[m];
        float dot = __fadd_rn(__fadd_rn(__fmul_rn(pn0, qm.x), __fmul_rn(pn1, qm.y)),
                              __fmul_rn(pn2, qm.z));
        float d2 = __fadd_rn(__fsub_rn(sqn, __fmul_rn(2.0f, dot)), qm.w);
        u32 u = __float_as_uint(d2);
        u = (u & 0x80000000u) ? ~u : (u | 0x80000000u);  // orderable
        u32 lo = (u << 11) | (u32)m;
        u32 hi = 0x43300000u | (u >> 21);
        kd[j] = __hiloint2double((int)hi, (int)lo);
    }

    // Phase 1: lane-minima (pairwise tree), 64-lane bitonic, T = 32nd smallest.
    double tmin[16];
#pragma unroll
    for (int j = 0; j < 16; ++j) tmin[j] = fmin(kd[j], kd[j + 16]);
#pragma unroll
    for (int j = 0; j < 8; ++j) tmin[j] = fmin(tmin[j], tmin[j + 8]);
#pragma unroll
    for (int j = 0; j < 4; ++j) tmin[j] = fmin(tmin[j], tmin[j + 4]);
    double lmin = fmin(fmin(tmin[0], tmin[2]), fmin(tmin[1], tmin[3]));
    double v = lmin;
#pragma unroll
    for (int k = 2; k <= 64; k <<= 1) {
#pragma unroll
        for (int j2 = k >> 1; j2 > 0; j2 >>= 1) {
            double o = __shfl_xor(v, j2);
            bool up = ((lane & k) == 0);
            bool low = ((lane & j2) == 0);
            double mn = fmin(v, o), mx = fmax(v, o);
            v = (up == low) ? mn : mx;
        }
    }
    double T = __shfl(v, 31);

    // Phase 2: pad + ballot-compact keys <= T into LDS.
#pragma unroll
    for (int s = 0; s < 4; ++s) cand[wv][lane + s * 64] = 1e300;
    int base = 0;
#pragma unroll
    for (int j = 0; j < 32; ++j) {
        bool pred = (kd[j] <= T);
        u64 bal = __ballot(pred);
        int prefix = (int)__popcll(bal & ((1ull << lane) - 1ull));
        int slot = base + prefix;
        if (pred && slot < 256) cand[wv][slot] = kd[j];
        base += (int)__popcll(bal);
    }

    if (base <= 256) {   // base >= 32 guaranteed (32 lane-minima <= T)
        double kc[4];
#pragma unroll
        for (int j = 0; j < 4; ++j) kc[j] = cand[wv][lane * 4 + j];
        bitonic256(kc, lane);
        if (lane < 8) {
            int4 w;
            w.x = __double2loint(kc[0]) & 2047;
            w.y = __double2loint(kc[1]) & 2047;
            w.z = __double2loint(kc[2]) & 2047;
            w.w = __double2loint(kc[3]) & 2047;
            *(int4*)&idxout[(size_t)p * 32 + lane * 4] = w;
        }
    } else {
        // Fallback: exact full-register selection (R9 path).
        double last = -1.0;
        for (int it = 0; it < 32; ++it) {
            double lm0 = 1e300, lm1 = 1e300;
#pragma unroll
            for (int j = 0; j < 32; j += 2) {
                double t0 = kd[j], t1 = kd[j + 1];
                lm0 = fmin(lm0, (t0 > last) ? t0 : 1e300);
                lm1 = fmin(lm1, (t1 > last) ? t1 : 1e300);
            }
            double lm = fmin(lm0, lm1);
#pragma unroll
            for (int off = 32; off; off >>= 1)
                lm = fmin(lm, __shfl_xor(lm, off));
            if (lane == 0) idxout[(size_t)p * 32 + it] = __double2loint(lm) & 2047;
            last = lm;
        }
    }
}

// ---------------------------------------------------------------------------
// UV GEMM: U[n][c] = x@(Wa1-Wa2)+ba  (f32, exact, read once per point);
//          V[n][c] = x@Wa2           (bf16, gathered 32x -> half traffic).
// A f32 -> split LDS, 3-term MFMA vs split weights (defines U/V precision).
// ---------------------------------------------------------------------------
template<int K, int KP, int N2>
__global__ __launch_bounds__(256) void uv_gemm(
    const float* __restrict__ xin, const u16* __restrict__ wT,
    const float* __restrict__ ba, float* __restrict__ Uf, u16* __restrict__ Vb)
{
    constexpr int SA = KP + 8;
    constexpr int WSZ = N2 * KP;
    constexpr int CMID = N2 / 2;
    __shared__ __align__(16) u16 AsH[32 * SA];
    __shared__ __align__(16) u16 AsL[32 * SA];
    int row0 = blockIdx.x * 32;
    int tid = threadIdx.x, lane = tid & 63, wv = tid >> 6, ln = lane & 15, q = lane >> 4;

    for (int e = tid; e < 32 * (KP / 8); e += 256) {
        int r = e / (KP / 8), c0 = (e % (KP / 8)) * 8;
        bf16x8 hv, lv;
#pragma unroll
        for (int jj = 0; jj < 8; ++jj) {
            int c = c0 + jj;
            float v = (c < K) ? xin[(size_t)(row0 + r) * K + c] : 0.f;
            u16 hi = f2b(v);
            hv[jj] = hi;
            lv[jj] = f2b(v - b2f(hi));
        }
        *(bf16x8*)&AsH[r * SA + c0] = hv;
        *(bf16x8*)&AsL[r * SA + c0] = lv;
    }
    __syncthreads();

    constexpr int NT = N2 / 64;
    f32x4 acc[2][NT] = {};
    const int wbase = wv * (N2 / 4);
#pragma unroll
    for (int ks = 0; ks < KP / 32; ++ks) {
        bf16x8 a0h = *(const bf16x8*)&AsH[(ln) * SA + ks * 32 + q * 8];
        bf16x8 a1h = *(const bf16x8*)&AsH[(16 + ln) * SA + ks * 32 + q * 8];
        bf16x8 a0l = *(const bf16x8*)&AsL[(ln) * SA + ks * 32 + q * 8];
        bf16x8 a1l = *(const bf16x8*)&AsL[(16 + ln) * SA + ks * 32 + q * 8];
#pragma unroll
        for (int nt = 0; nt < NT; ++nt) {
            size_t wi = (size_t)(wbase + nt * 16 + ln) * KP + ks * 32 + q * 8;
            bf16x8 bh = *(const bf16x8*)&wT[wi];
            bf16x8 bl = *(const bf16x8*)&wT[WSZ + wi];
            acc[0][nt] = mfma16(a0h, bh, acc[0][nt]);
            acc[0][nt] = mfma16(a0h, bl, acc[0][nt]);
            acc[0][nt] = mfma16(a0l, bh, acc[0][nt]);
            acc[1][nt] = mfma16(a1h, bh, acc[1][nt]);
            acc[1][nt] = mfma16(a1h, bl, acc[1][nt]);
            acc[1][nt] = mfma16(a1l, bh, acc[1][nt]);
        }
    }
#pragma unroll
    for (int nt = 0; nt < NT; ++nt) {
        int col = wbase + nt * 16 + ln;
#pragma unroll
        for (int mt = 0; mt < 2; ++mt)
#pragma unroll
            for (int r = 0; r < 4; ++r) {
                size_t row = (size_t)(row0 + mt * 16 + q * 4 + r);
                if (col < CMID)
                    Uf[row * CMID + col] = acc[mt][nt][r] + ba[col];
                else
                    Vb[row * CMID + (col - CMID)] = f2b(acc[mt][nt][r]);
            }
    }
}

// ---------------------------------------------------------------------------
// Edge pool — R2-PROVEN config (90-92us measured; R16 laws: PTS=2, (256,4),
// NTP<=2, 1-term Wb). R3/R4 register-hoist variants REFUTED: allocator pins
// 64 VGPR under (256,4) and spills (R3: +10MB scratch) or rematerializes +
// loses occupancy under (256,3) (R4: 39%->30%). Do not re-attempt A-frag
// register residency with this structure.
// R1: ks loop unrolled + 1-deep weight prefetch (bh/bhn); conversion
// loop unrolled. Tripwire: WRITE_SIZE ~= output, VGPR=64, occ ~39%.
// ---------------------------------------------------------------------------
template<int CMID, int COUT, bool OUTB, int PTS, int NTP>
__global__ __launch_bounds__(256, 4) void edge_pool(
    const float* __restrict__ Uf, const u16* __restrict__ Vb,
    const int* __restrict__ idx,
    const u16* __restrict__ wbT, const float* __restrict__ bb,
    void* __restrict__ outp)
{
    constexpr int KC = CMID / 32;
    constexpr int C8 = CMID / 8;
    constexpr int NTW = COUT / 64;
    constexpr int CITER = PTS * 32 * C8 / 256;  // exact (divisible)
    __shared__ __align__(16) u16 hfrag[PTS * 2 * KC * 512];
    __shared__ int nbr[PTS * 32];

    int tid = threadIdx.x, lane = tid & 63, wv = tid >> 6, ln = lane & 15, q = lane >> 4;
    int p0 = blockIdx.x * PTS;

    if (tid < PTS * 32) {
        int pt = tid >> 5, kk = tid & 31;
        int p = p0 + pt;
        nbr[tid] = ((p >> 11) << 11) + (idx[(size_t)p * 32 + kk] & 2047);
    }
    __syncthreads();

    // build h in swizzled fragment order (packed conversion), unrolled so the
    // per-iteration gather/U loads issue back-to-back and pipeline
#pragma unroll
    for (int e0 = 0; e0 < CITER; ++e0) {
        int e = tid + e0 * 256;
        int pt = e / (32 * C8), rem = e % (32 * C8), r = rem / C8, c8 = rem % C8;
        const float* U = &Uf[(size_t)(p0 + pt) * CMID + c8 * 8];
        bf16x8 vb = *(const bf16x8*)&Vb[(size_t)nbr[pt * 32 + r] * CMID + c8 * 8];
        u32x4 hq;
#pragma unroll
        for (int jj = 0; jj < 4; ++jj) {
            float f0 = U[2 * jj]     + b2f((u16)vb[2 * jj]);
            float f1 = U[2 * jj + 1] + b2f((u16)vb[2 * jj + 1]);
            f0 = f0 >= 0.f ? f0 : 0.2f * f0;
            f1 = f1 >= 0.f ? f1 : 0.2f * f1;
            u32 a = __float_as_uint(f0) + 0x8000u;
            u32 b = __float_as_uint(f1) + 0x8000u;
            hq[jj] = __builtin_amdgcn_perm(b, a, 0x07060302u);  // hi16(f1)<<16|hi16(f0)
        }
        int mt = r >> 4, lnr = r & 15, ks = c8 >> 2, qq = c8 & 3;
        int slot = qq * 16 + (lnr ^ ((ks << 2) | qq));
        *(u32x4*)&hfrag[(((pt * 2 + mt) * KC + ks) * 64 + slot) * 8] = hq;
    }
    __syncthreads();

    for (int ng = 0; ng < NTW; ng += NTP) {
        f32x4 acc[PTS][2][NTP] = {};  // [pt][mt][nt]
        bf16x8 bh[NTP];
#pragma unroll
        for (int nt = 0; nt < NTP; ++nt) {
            size_t wi = ((size_t)((wv * NTW + ng + nt) * KC + 0) * 64 + lane) * 8;
            bh[nt] = *(const bf16x8*)&wbT[wi];
        }
#pragma unroll
        for (int ks = 0; ks < KC; ++ks) {
            bf16x8 bhn[NTP];
            if (ks + 1 < KC) {
#pragma unroll
                for (int nt = 0; nt < NTP; ++nt) {
                    size_t wi = ((size_t)((wv * NTW + ng + nt) * KC + (ks + 1)) * 64 + lane) * 8;
                    bhn[nt] = *(const bf16x8*)&wbT[wi];
                }
            }
            int slot = q * 16 + (ln ^ ((ks << 2) | q));
#pragma unroll
            for (int pt = 0; pt < PTS; ++pt)
#pragma unroll
                for (int mt = 0; mt < 2; ++mt) {
                    bf16x8 a = *(const bf16x8*)
                        &hfrag[(((pt * 2 + mt) * KC + ks) * 64 + slot) * 8];
#pragma unroll
                    for (int nt = 0; nt < NTP; ++nt)
                        acc[pt][mt][nt] = mfma16(a, bh[nt], acc[pt][mt][nt]);
                }
            if (ks + 1 < KC) {
#pragma unroll
                for (int nt = 0; nt < NTP; ++nt) bh[nt] = bhn[nt];
            }
        }
        // per-point max over 32 rows, bias+lrelu, store (frees accs)
#pragma unroll
        for (int pt = 0; pt < PTS; ++pt)
#pragma unroll
            for (int nt = 0; nt < NTP; ++nt) {
                int col = wv * (COUT / 4) + (ng + nt) * 16 + ln;
                float m = acc[pt][0][nt][0];
#pragma unroll
                for (int r = 1; r < 4; ++r) m = fmaxf(m, acc[pt][0][nt][r]);
#pragma unroll
                for (int r = 0; r < 4; ++r) m = fmaxf(m, acc[pt][1][nt][r]);
                m = fmaxf(m, __shfl_xor(m, 16));
                m = fmaxf(m, __shfl_xor(m, 32));
                if (q == 0) {
                    float v = m + bb[col];
                    v = v >= 0.f ? v : 0.2f * v;
                    if constexpr (OUTB)
                        ((u16*)outp)[(size_t)(p0 + pt) * COUT + col] = f2b(v);
                    else
                        ((float*)outp)[(size_t)(p0 + pt) * COUT + col] = v;
                }
            }
    }
}

// ---------------------------------------------------------------------------
// head123 (R7+R8 fusion): stage 1 = head1 (concat 704 -> 512, lrelu),
// bit-identical; 32x512 bf16 tile -> LDS Bs [32][520] (overlays AsH/AsL).
// Stage 2 = head_bf<512,256> body verbatim; its 32x256 bf16 output goes to
// LDS Bs2 [32][264] (overlays Bs after barrier) instead of HBM h2.
// Stage 3 = head_gemm3 body verbatim, wave 0 only (identical ks order and
// acc chains) -> final f32 out. Eliminates h1 (16MB W+R, R7) and h2
// (8MB W+R, R8) HBM round-trips + 2 launches. Output bit-identical.
// ---------------------------------------------------------------------------
__global__ __launch_bounds__(256) void head123(
    const float* __restrict__ x1, const float* __restrict__ x2,
    const u16* __restrict__ x3,
    const u16* __restrict__ wT1, const float* __restrict__ b1,
    const u16* __restrict__ wT2, const float* __restrict__ b2,
    const u16* __restrict__ wT3, const float* __restrict__ b3,
    float* __restrict__ out3)
{
    constexpr int KD = 704, KT = 352, SA = 360, SB = 520, SB3 = 264;
    __shared__ __align__(16) u16 lds[2 * 32 * SA];   // 46080 B
    u16* AsH = lds;
    u16* AsL = lds + 32 * SA;
    u16* Bs  = lds;                                  // stage-2 overlay [32][SB]
    u16* Bs2 = lds;                                  // stage-3 overlay [32][SB3]
    int row0 = blockIdx.x * 32;
    int tid = threadIdx.x, lane = tid & 63, wv = tid >> 6, ln = lane & 15, q = lane >> 4;

    f32x4 acc[2][8] = {};
    const int wbase = wv * 128;

    for (int ph = 0; ph < 2; ++ph) {
        if (ph) __syncthreads();
        for (int e = tid; e < 32 * 44; e += 256) {
            int r = e / 44, c8l = e % 44;
            int c = ph * KT + c8l * 8;
            int g = row0 + r;
            int a = r * SA + c8l * 8;
            if (c < 192) {
                const float* src = (c < 64) ? &x1[(size_t)g * 64 + c]
                                            : &x2[(size_t)g * 128 + (c - 64)];
                bf16x8 hv, lv;
#pragma unroll
                for (int jj = 0; jj < 8; ++jj) {
                    float v = src[jj];
                    u16 hi = f2b(v);
                    hv[jj] = hi;
                    lv[jj] = f2b(v - b2f(hi));
                }
                *(bf16x8*)&AsH[a] = hv;
                *(bf16x8*)&AsL[a] = lv;
            } else {
                *(bf16x8*)&AsH[a] = *(const bf16x8*)&x3[(size_t)g * 512 + (c - 192)];
                bf16x8 z = {0, 0, 0, 0, 0, 0, 0, 0};
                *(bf16x8*)&AsL[a] = z;
            }
        }
        __syncthreads();
        for (int ks = 0; ks < 11; ++ks) {
            int gk = ph * 11 + ks;
            bool t3 = (gk < 6);
            bf16x8 a0h = *(const bf16x8*)&AsH[(ln) * SA + ks * 32 + q * 8];
            bf16x8 a1h = *(const bf16x8*)&AsH[(16 + ln) * SA + ks * 32 + q * 8];
            bf16x8 a0l = *(const bf16x8*)&AsL[(ln) * SA + ks * 32 + q * 8];
            bf16x8 a1l = *(const bf16x8*)&AsL[(16 + ln) * SA + ks * 32 + q * 8];
#pragma unroll
            for (int nt = 0; nt < 8; ++nt) {
                size_t wi = (size_t)(wbase + nt * 16 + ln) * KD + gk * 32 + q * 8;
                bf16x8 bh = *(const bf16x8*)&wT1[wi];
                acc[0][nt] = mfma16(a0h, bh, acc[0][nt]);
                acc[1][nt] = mfma16(a1h, bh, acc[1][nt]);
                if (t3) {
                    acc[0][nt] = mfma16(a0l, bh, acc[0][nt]);
                    acc[1][nt] = mfma16(a1l, bh, acc[1][nt]);
                }
            }
        }
    }
    // stage-1 epilogue -> LDS exchange (bit-identical values to old h1)
    __syncthreads();   // all AsH/AsL reads done before overlay
#pragma unroll
    for (int nt = 0; nt < 8; ++nt) {
        int col = wbase + nt * 16 + ln;
        float bv = b1[col];
#pragma unroll
        for (int mt = 0; mt < 2; ++mt)
#pragma unroll
            for (int r = 0; r < 4; ++r) {
                float v = acc[mt][nt][r] + bv;
                v = v >= 0.f ? v : 0.2f * v;
                Bs[(mt * 16 + q * 4 + r) * SB + col] = f2b(v);
            }
    }
    __syncthreads();

    // stage 2: head_bf<512,256> body (verbatim indexing, SA -> SB)
    f32x4 acc2[2][4] = {};
    const int wbase2 = wv * 64;
    for (int ks = 0; ks < 16; ++ks) {
        bf16x8 a0 = *(const bf16x8*)&Bs[(ln) * SB + ks * 32 + q * 8];
        bf16x8 a1 = *(const bf16x8*)&Bs[(16 + ln) * SB + ks * 32 + q * 8];
#pragma unroll
        for (int nt = 0; nt < 4; ++nt) {
            size_t wi = (size_t)(wbase2 + nt * 16 + ln) * 512 + ks * 32 + q * 8;
            bf16x8 bh = *(const bf16x8*)&wT2[wi];
            acc2[0][nt] = mfma16(a0, bh, acc2[0][nt]);
            acc2[1][nt] = mfma16(a1, bh, acc2[1][nt]);
        }
    }
    // stage-2 epilogue -> LDS exchange Bs2 (bit-identical values to old h2)
    __syncthreads();   // all Bs reads done before overlay
#pragma unroll
    for (int nt = 0; nt < 4; ++nt) {
        int col = wbase2 + nt * 16 + ln;
        float bv = b2[col];
#pragma unroll
        for (int mt = 0; mt < 2; ++mt)
#pragma unroll
            for (int r = 0; r < 4; ++r) {
                float v = acc2[mt][nt][r] + bv;
                v = v >= 0.f ? v : 0.2f * v;
                Bs2[(mt * 16 + q * 4 + r) * SB3 + col] = f2b(v);
            }
    }
    __syncthreads();

    // stage 3: head_gemm3 body (verbatim ks order/acc chains), wave 0 only
    if (wv == 0) {
        f32x4 acc3[2] = {};
#pragma unroll
        for (int ks = 0; ks < 8; ++ks) {
            bf16x8 a0 = *(const bf16x8*)&Bs2[(ln) * SB3 + ks * 32 + q * 8];
            bf16x8 a1 = *(const bf16x8*)&Bs2[(16 + ln) * SB3 + ks * 32 + q * 8];
            size_t wi = (size_t)ln * 256 + ks * 32 + q * 8;
            bf16x8 bh = *(const bf16x8*)&wT3[wi];
            acc3[0] = mfma16(a0, bh, acc3[0]);
            acc3[1] = mfma16(a1, bh, acc3[1]);
        }
        if (ln < 12) {
            float bv = b3[ln];
#pragma unroll
            for (int mt = 0; mt < 2; ++mt)
#pragma unroll
                for (int r = 0; r < 4; ++r)
                    out3[(size_t)(row0 + mt * 16 + q * 4 + r) * 12 + ln] = acc3[mt][r] + bv;
        }
    }
}

// ---------------------------------------------------------------------------
// Workspace (peak 50,708,480 B = 48.4 MB):
//   [0,        2473984)  split weights
//   [2473984,  4571136)  idxb
//   [4571136,  8765440)  x1 f32      (pos4 256KB overlays head during
//                        prep+knn; x1 written after knn -> safe)
//   [8765440, 17154048)  x2 f32
//   [17154048,33931264)  Uf f32 (<=8MB) @ +0, Vb bf16 (<=4MB) @ +8MB
//                        (R8: h1/h2 eliminated entirely — head123 keeps all
//                        intermediates in LDS)
//   [33931264,50708480)  x3 bf16
// ---------------------------------------------------------------------------
extern "C" void kernel_launch(void* const* d_in, const int* in_sizes, int n_in,
                              void* d_out, int out_size, void* d_ws, size_t ws_size,
                              hipStream_t stream)
{
    (void)in_sizes; (void)n_in; (void)out_size; (void)ws_size;
    const float* x   = (const float*)d_in[0];
    const float* pos = (const float*)d_in[1];
    const float* w1a = (const float*)d_in[2];  const float* b1a = (const float*)d_in[3];
    const float* w1b = (const float*)d_in[4];  const float* b1b = (const float*)d_in[5];
    const float* w2a = (const float*)d_in[6];  const float* b2a = (const float*)d_in[7];
    const float* w2b = (const float*)d_in[8];  const float* b2b = (const float*)d_in[9];
    const float* w3a = (const float*)d_in[10]; const float* b3a = (const float*)d_in[11];
    const float* w3b = (const float*)d_in[12]; const float* b3b = (const float*)d_in[13];
    const float* wf1 = (const float*)d_in[14]; const float* bf1 = (const float*)d_in[15];
    const float* wf2 = (const float*)d_in[16]; const float* bf2 = (const float*)d_in[17];
    const float* wf3 = (const float*)d_in[18]; const float* bf3 = (const float*)d_in[19];

    char* ws = (char*)d_ws;
    u16* t1uv = (u16*)(ws + 0);
    u16* t2uv = (u16*)(ws + 16384);
    u16* t3uv = (u16*)(ws + 49152);
    u16* t1b  = (u16*)(ws + 180224);
    u16* t2b  = (u16*)(ws + 196608);
    u16* t3b  = (u16*)(ws + 229376);
    u16* tf1  = (u16*)(ws + 491520);
    u16* tf2  = (u16*)(ws + 1933312);
    u16* tf3  = (u16*)(ws + 2457600);
    int*   idxb = (int*)(ws + 2473984);
    float* x1 = (float*)(ws + 4571136);
    float* x2 = (float*)(ws + 8765440);
    float* Uf = (float*)(ws + 17154048);           // <= 8 MB (edge3)
    u16*   Vb = (u16*)(ws + 17154048 + 8388608);   // <= 4 MB (edge3)
    u16*   x3 = (u16*)(ws + 33931264);
    float4* pos4 = (float4*)(ws + 4571136);  // 256KB, dead after knn (x1 overlays)

    prep_weights<<<2480, 256, 0, stream>>>(w1a, w1b, w2a, w2b, w3a, w3b, wf1, wf2, wf3,
                                           pos, t1uv, t2uv, t3uv, t1b, t2b, t3b,
                                           tf1, tf2, tf3, pos4);
    knn_kernel<<<4096, 256, 0, stream>>>(pos4, idxb);
    uv_gemm<  3, 32, 128><<<512, 256, 0, stream>>>(x,  t1uv, b1a, Uf, Vb);
    edge_pool< 64,  64, false, 2, 1><<<8192, 256, 0, stream>>>(Uf, Vb, idxb, t1b, b1b, x1);
    uv_gemm< 64, 64, 128><<<512, 256, 0, stream>>>(x1, t2uv, b2a, Uf, Vb);
    edge_pool< 64, 128, false, 2, 2><<<8192, 256, 0, stream>>>(Uf, Vb, idxb, t2b, b2b, x2);
    uv_gemm<128, 128, 256><<<512, 256, 0, stream>>>(x2, t3uv, b3a, Uf, Vb);
    edge_pool<128, 512, true, 2, 2><<<8192, 256, 0, stream>>>(Uf, Vb, idxb, t3b, b3b, x3);
    head123<<<512, 256, 0, stream>>>(x1, x2, x3, tf1, bf1, tf2, bf2, tf3, bf3,
                                     (float*)d_out);
}

// Round 10
// 364.749 us; speedup vs baseline: 1.0537x; 1.0197x over previous
//
#include <hip/hip_runtime.h>

typedef unsigned short u16;
typedef unsigned int u32;
typedef unsigned long long u64;
typedef short bf16x8 __attribute__((ext_vector_type(8)));
typedef float f32x4 __attribute__((ext_vector_type(4)));
typedef u32 u32x4 __attribute__((ext_vector_type(4)));

__device__ __forceinline__ float b2f(u16 u) {
    return __uint_as_float(((u32)u) << 16);
}
__device__ __forceinline__ u16 f2b(float f) {  // RNE
    u32 u = __float_as_uint(f);
    u32 r = u + 0x7fffu + ((u >> 16) & 1u);
    return (u16)(r >> 16);
}
__device__ __forceinline__ f32x4 mfma16(bf16x8 a, bf16x8 b, f32x4 c) {
    return __builtin_amdgcn_mfma_f32_16x16x32_bf16(a, b, c, 0, 0, 0);
}

// ---------------------------------------------------------------------------
// prep: weights. seg -> W^T[n][k] row-major split bf16 (hi, lo planes).
// seg_bf -> MFMA B-fragment order: [tile][ks][lane][8]. seg_uv -> stacked
// [(Wa1-Wa2)^T ; Wa2^T]. R6: final segment builds pos4[m] = {x,y,z, sum(q^2)}
// with the EXACT __fmul_rn/__fadd_rn sequence knn used in-loop (bit-same).
// ---------------------------------------------------------------------------
template<int NP, int KP, int R, int C>
__device__ __forceinline__ bool seg(int t, int base, const float* src, u16* dst) {
    int r = t - base;
    if (r < 0) return true;
    constexpr int RNG = NP * KP;
    if (r >= RNG) return false;
    int n = r / KP, k = r - n * KP;
    float v = (k < R && n < C) ? src[k * C + n] : 0.f;
    u16 hi = f2b(v);
    dst[r] = hi;
    dst[RNG + r] = f2b(v - b2f(hi));
    return true;
}
template<int NP, int KP, int R, int C>
__device__ __forceinline__ bool seg_bf(int t, int base, const float* src, u16* dst) {
    int r = t - base;
    if (r < 0) return true;
    constexpr int RNG = NP * KP;
    if (r >= RNG) return false;
    constexpr int KC = KP / 32;
    int j = r & 7, s = r >> 3;
    int lanei = s & 63;
    int ks = (s >> 6) % KC, tile = (s >> 6) / KC;
    int n = tile * 16 + (lanei & 15);
    int k = ks * 32 + (lanei >> 4) * 8 + j;
    float v = (k < R && n < C) ? src[k * C + n] : 0.f;
    u16 hi = f2b(v);
    dst[r] = hi;
    dst[RNG + r] = f2b(v - b2f(hi));
    return true;
}
template<int CMID, int CIN, int KP>
__device__ __forceinline__ bool seg_uv(int t, int base, const float* wa, u16* dst) {
    int r = t - base;
    if (r < 0) return true;
    constexpr int RNG = 2 * CMID * KP;
    if (r >= RNG) return false;
    int n = r / KP, k = r - n * KP;
    float v = 0.f;
    if (k < CIN) {
        if (n < CMID) v = wa[k * CMID + n] - wa[(CIN + k) * CMID + n];
        else          v = wa[(CIN + k) * CMID + (n - CMID)];
    }
    u16 hi = f2b(v);
    dst[r] = hi;
    dst[RNG + r] = f2b(v - b2f(hi));
    return true;
}

__global__ __launch_bounds__(256) void prep_weights(
    const float* w1a, const float* w1b, const float* w2a, const float* w2b,
    const float* w3a, const float* w3b, const float* wf1, const float* wf2,
    const float* wf3, const float* pos,
    u16* t1uv, u16* t2uv, u16* t3uv, u16* t1b, u16* t2b, u16* t3b,
    u16* tf1, u16* tf2, u16* tf3, float4* pos4)
{
    int t = blockIdx.x * 256 + threadIdx.x;
    if (seg_uv< 64,   3,  32>(t,      0, w1a, t1uv)) return;
    if (seg_uv< 64,  64,  64>(t,   4096, w2a, t2uv)) return;
    if (seg_uv<128, 128, 128>(t,  12288, w3a, t3uv)) return;
    if (seg_bf< 64,  64,  64,  64>(t,  45056, w1b, t1b)) return;
    if (seg_bf<128,  64,  64, 128>(t,  49152, w2b, t2b)) return;
    if (seg_bf<512, 128, 128, 512>(t,  57344, w3b, t3b)) return;
    if (seg<512, 704, 704, 512>(t, 122880, wf1, tf1)) return;
    if (seg<256, 512, 512, 256>(t, 483328, wf2, tf2)) return;
    if (seg< 16, 256, 256,  12>(t, 614400, wf3, tf3)) return;
    int r = t - 618496;
    if (r >= 0 && r < 16384) {
        const float* q = pos + (size_t)r * 3;
        float q0 = q[0], q1 = q[1], q2 = q[2];
        float sqm = __fadd_rn(__fadd_rn(__fmul_rn(q0, q0), __fmul_rn(q1, q1)),
                              __fmul_rn(q2, q2));
        float4 v; v.x = q0; v.y = q1; v.z = q2; v.w = sqm;
        pos4[r] = v;
    }
}

// ---------------------------------------------------------------------------
// kNN: one WAVE per point. Key = 2^52 + ((orderable(d2) << 11) | idx) built
// via BIT-PACKING. fmin/fmax = exact lexicographic (d2, idx) compare.
// R6: pos as coalesced float4 {x,y,z,sq}. Phase 1: T = 32nd-smallest of
// lane-minima (R5 pairwise-tree lane-min + 64-lane bitonic). Phase 2:
// ballot-compact keys <= T into LDS. R2: 256-element register bitonic sort,
// first 32 = lanes 0..7 store int4. Gate -> exact fallback.
// ---------------------------------------------------------------------------
__device__ __forceinline__ void bitonic256(double v[4], int lane) {
#pragma unroll
    for (int k = 2; k <= 256; k <<= 1) {
#pragma unroll
        for (int j = k >> 1; j > 0; j >>= 1) {
            if (j >= 4) {
                int lj = j >> 2;
                bool upLane = ((lane & (k >> 2)) == 0);   // k>=8 here; r&k==0
                bool lowLane = ((lane & lj) == 0);
                bool keepMin = (upLane == lowLane);
#pragma unroll
                for (int r = 0; r < 4; ++r) {
                    double o = __shfl_xor(v[r], lj);
                    double mn = fmin(v[r], o), mx = fmax(v[r], o);
                    v[r] = keepMin ? mn : mx;
                }
            } else {
#pragma unroll
                for (int r = 0; r < 4; ++r) {
                    if ((r & j) == 0) {
                        int r2 = r | j;
                        bool up = (((lane * 4 + r) & k) == 0);
                        double mn = fmin(v[r], v[r2]), mx = fmax(v[r], v[r2]);
                        v[r] = up ? mn : mx;
                        v[r2] = up ? mx : mn;
                    }
                }
            }
        }
    }
}

__global__ __launch_bounds__(256) void knn_kernel(const float4* __restrict__ pos4,
                                                  int* __restrict__ idxout)
{
    int tid = threadIdx.x, lane = tid & 63, wv = tid >> 6;
    int p = blockIdx.x * 4 + wv;
    int b = p >> 11, n = p & 2047;
    __shared__ double cand[4][256];
    const float4* pb4 = pos4 + (size_t)b * 2048;
    float4 pn = pb4[n];
    float pn0 = pn.x, pn1 = pn.y, pn2 = pn.z, sqn = pn.w;
    double kd[32];
#pragma unroll
    for (int j = 0; j < 32; ++j) {
        int m = lane + j * 64;
        float4 qm = pb4[m];
        float dot = __fadd_rn(__fadd_rn(__fmul_rn(pn0, qm.x), __fmul_rn(pn1, qm.y)),
                              __fmul_rn(pn2, qm.z));
        float d2 = __fadd_rn(__fsub_rn(sqn, __fmul_rn(2.0f, dot)), qm.w);
        u32 u = __float_as_uint(d2);
        u = (u & 0x80000000u) ? ~u : (u | 0x80000000u);  // orderable
        u32 lo = (u << 11) | (u32)m;
        u32 hi = 0x43300000u | (u >> 21);
        kd[j] = __hiloint2double((int)hi, (int)lo);
    }

    // Phase 1: lane-minima (pairwise tree), 64-lane bitonic, T = 32nd smallest.
    double tmin[16];
#pragma unroll
    for (int j = 0; j < 16; ++j) tmin[j] = fmin(kd[j], kd[j + 16]);
#pragma unroll
    for (int j = 0; j < 8; ++j) tmin[j] = fmin(tmin[j], tmin[j + 8]);
#pragma unroll
    for (int j = 0; j < 4; ++j) tmin[j] = fmin(tmin[j], tmin[j + 4]);
    double lmin = fmin(fmin(tmin[0], tmin[2]), fmin(tmin[1], tmin[3]));
    double v = lmin;
#pragma unroll
    for (int k = 2; k <= 64; k <<= 1) {
#pragma unroll
        for (int j2 = k >> 1; j2 > 0; j2 >>= 1) {
            double o = __shfl_xor(v, j2);
            bool up = ((lane & k) == 0);
            bool low = ((lane & j2) == 0);
            double mn = fmin(v, o), mx = fmax(v, o);
            v = (up == low) ? mn : mx;
        }
    }
    double T = __shfl(v, 31);

    // Phase 2: pad + ballot-compact keys <= T into LDS.
#pragma unroll
    for (int s = 0; s < 4; ++s) cand[wv][lane + s * 64] = 1e300;
    int base = 0;
#pragma unroll
    for (int j = 0; j < 32; ++j) {
        bool pred = (kd[j] <= T);
        u64 bal = __ballot(pred);
        int prefix = (int)__popcll(bal & ((1ull << lane) - 1ull));
        int slot = base + prefix;
        if (pred && slot < 256) cand[wv][slot] = kd[j];
        base += (int)__popcll(bal);
    }

    if (base <= 256) {   // base >= 32 guaranteed (32 lane-minima <= T)
        double kc[4];
#pragma unroll
        for (int j = 0; j < 4; ++j) kc[j] = cand[wv][lane * 4 + j];
        bitonic256(kc, lane);
        if (lane < 8) {
            int4 w;
            w.x = __double2loint(kc[0]) & 2047;
            w.y = __double2loint(kc[1]) & 2047;
            w.z = __double2loint(kc[2]) & 2047;
            w.w = __double2loint(kc[3]) & 2047;
            *(int4*)&idxout[(size_t)p * 32 + lane * 4] = w;
        }
    } else {
        // Fallback: exact full-register selection (R9 path).
        double last = -1.0;
        for (int it = 0; it < 32; ++it) {
            double lm0 = 1e300, lm1 = 1e300;
#pragma unroll
            for (int j = 0; j < 32; j += 2) {
                double t0 = kd[j], t1 = kd[j + 1];
                lm0 = fmin(lm0, (t0 > last) ? t0 : 1e300);
                lm1 = fmin(lm1, (t1 > last) ? t1 : 1e300);
            }
            double lm = fmin(lm0, lm1);
#pragma unroll
            for (int off = 32; off; off >>= 1)
                lm = fmin(lm, __shfl_xor(lm, off));
            if (lane == 0) idxout[(size_t)p * 32 + it] = __double2loint(lm) & 2047;
            last = lm;
        }
    }
}

// ---------------------------------------------------------------------------
// UV GEMM: U[n][c] = x@(Wa1-Wa2)+ba  (f32, exact, read once per point);
//          V[n][c] = x@Wa2           (bf16, gathered 32x -> half traffic).
// A f32 -> split LDS, 3-term MFMA vs split weights (defines U/V precision).
// ---------------------------------------------------------------------------
template<int K, int KP, int N2>
__global__ __launch_bounds__(256) void uv_gemm(
    const float* __restrict__ xin, const u16* __restrict__ wT,
    const float* __restrict__ ba, float* __restrict__ Uf, u16* __restrict__ Vb)
{
    constexpr int SA = KP + 8;
    constexpr int WSZ = N2 * KP;
    constexpr int CMID = N2 / 2;
    __shared__ __align__(16) u16 AsH[32 * SA];
    __shared__ __align__(16) u16 AsL[32 * SA];
    int row0 = blockIdx.x * 32;
    int tid = threadIdx.x, lane = tid & 63, wv = tid >> 6, ln = lane & 15, q = lane >> 4;

    for (int e = tid; e < 32 * (KP / 8); e += 256) {
        int r = e / (KP / 8), c0 = (e % (KP / 8)) * 8;
        bf16x8 hv, lv;
#pragma unroll
        for (int jj = 0; jj < 8; ++jj) {
            int c = c0 + jj;
            float v = (c < K) ? xin[(size_t)(row0 + r) * K + c] : 0.f;
            u16 hi = f2b(v);
            hv[jj] = hi;
            lv[jj] = f2b(v - b2f(hi));
        }
        *(bf16x8*)&AsH[r * SA + c0] = hv;
        *(bf16x8*)&AsL[r * SA + c0] = lv;
    }
    __syncthreads();

    constexpr int NT = N2 / 64;
    f32x4 acc[2][NT] = {};
    const int wbase = wv * (N2 / 4);
#pragma unroll
    for (int ks = 0; ks < KP / 32; ++ks) {
        bf16x8 a0h = *(const bf16x8*)&AsH[(ln) * SA + ks * 32 + q * 8];
        bf16x8 a1h = *(const bf16x8*)&AsH[(16 + ln) * SA + ks * 32 + q * 8];
        bf16x8 a0l = *(const bf16x8*)&AsL[(ln) * SA + ks * 32 + q * 8];
        bf16x8 a1l = *(const bf16x8*)&AsL[(16 + ln) * SA + ks * 32 + q * 8];
#pragma unroll
        for (int nt = 0; nt < NT; ++nt) {
            size_t wi = (size_t)(wbase + nt * 16 + ln) * KP + ks * 32 + q * 8;
            bf16x8 bh = *(const bf16x8*)&wT[wi];
            bf16x8 bl = *(const bf16x8*)&wT[WSZ + wi];
            acc[0][nt] = mfma16(a0h, bh, acc[0][nt]);
            acc[0][nt] = mfma16(a0h, bl, acc[0][nt]);
            acc[0][nt] = mfma16(a0l, bh, acc[0][nt]);
            acc[1][nt] = mfma16(a1h, bh, acc[1][nt]);
            acc[1][nt] = mfma16(a1h, bl, acc[1][nt]);
            acc[1][nt] = mfma16(a1l, bh, acc[1][nt]);
        }
    }
#pragma unroll
    for (int nt = 0; nt < NT; ++nt) {
        int col = wbase + nt * 16 + ln;
#pragma unroll
        for (int mt = 0; mt < 2; ++mt)
#pragma unroll
            for (int r = 0; r < 4; ++r) {
                size_t row = (size_t)(row0 + mt * 16 + q * 4 + r);
                if (col < CMID)
                    Uf[row * CMID + col] = acc[mt][nt][r] + ba[col];
                else
                    Vb[row * CMID + (col - CMID)] = f2b(acc[mt][nt][r]);
            }
    }
}

// ---------------------------------------------------------------------------
// Edge pool — R2-PROVEN config (90-92us measured; R16 laws: PTS=2, (256,4),
// NTP<=2, 1-term Wb). R3/R4 register-hoist variants REFUTED (allocator pins
// 64 VGPR; spills or loses occupancy). R1: ks unroll + 1-deep weight
// prefetch; conversion unroll.
// R9: XCD-aware chunked blockIdx swizzle — 8192 blocks = 8 batches x 1024;
// wgid=(bid&7)*cpx+(bid>>3) puts one BATCH per XCD, so each XCD's private
// L2 holds its own batch's Vb slice (256-512KB << 4MB) and the neighbor
// gathers become L2-hits instead of cross-XCD redundant HBM fetches.
// Bijective (nwg%8==0). Tripwire: FETCH_SIZE 21.5 -> ~15MB, else revert.
// ---------------------------------------------------------------------------
template<int CMID, int COUT, bool OUTB, int PTS, int NTP>
__global__ __launch_bounds__(256, 4) void edge_pool(
    const float* __restrict__ Uf, const u16* __restrict__ Vb,
    const int* __restrict__ idx,
    const u16* __restrict__ wbT, const float* __restrict__ bb,
    void* __restrict__ outp)
{
    constexpr int KC = CMID / 32;
    constexpr int C8 = CMID / 8;
    constexpr int NTW = COUT / 64;
    constexpr int CITER = PTS * 32 * C8 / 256;  // exact (divisible)
    __shared__ __align__(16) u16 hfrag[PTS * 2 * KC * 512];
    __shared__ int nbr[PTS * 32];

    int tid = threadIdx.x, lane = tid & 63, wv = tid >> 6, ln = lane & 15, q = lane >> 4;
    int cpx = gridDim.x >> 3;
    int wgid = (blockIdx.x & 7) * cpx + (blockIdx.x >> 3);  // batch-per-XCD
    int p0 = wgid * PTS;

    if (tid < PTS * 32) {
        int pt = tid >> 5, kk = tid & 31;
        int p = p0 + pt;
        nbr[tid] = ((p >> 11) << 11) + (idx[(size_t)p * 32 + kk] & 2047);
    }
    __syncthreads();

    // build h in swizzled fragment order (packed conversion), unrolled so the
    // per-iteration gather/U loads issue back-to-back and pipeline
#pragma unroll
    for (int e0 = 0; e0 < CITER; ++e0) {
        int e = tid + e0 * 256;
        int pt = e / (32 * C8), rem = e % (32 * C8), r = rem / C8, c8 = rem % C8;
        const float* U = &Uf[(size_t)(p0 + pt) * CMID + c8 * 8];
        bf16x8 vb = *(const bf16x8*)&Vb[(size_t)nbr[pt * 32 + r] * CMID + c8 * 8];
        u32x4 hq;
#pragma unroll
        for (int jj = 0; jj < 4; ++jj) {
            float f0 = U[2 * jj]     + b2f((u16)vb[2 * jj]);
            float f1 = U[2 * jj + 1] + b2f((u16)vb[2 * jj + 1]);
            f0 = f0 >= 0.f ? f0 : 0.2f * f0;
            f1 = f1 >= 0.f ? f1 : 0.2f * f1;
            u32 a = __float_as_uint(f0) + 0x8000u;
            u32 b = __float_as_uint(f1) + 0x8000u;
            hq[jj] = __builtin_amdgcn_perm(b, a, 0x07060302u);  // hi16(f1)<<16|hi16(f0)
        }
        int mt = r >> 4, lnr = r & 15, ks = c8 >> 2, qq = c8 & 3;
        int slot = qq * 16 + (lnr ^ ((ks << 2) | qq));
        *(u32x4*)&hfrag[(((pt * 2 + mt) * KC + ks) * 64 + slot) * 8] = hq;
    }
    __syncthreads();

    for (int ng = 0; ng < NTW; ng += NTP) {
        f32x4 acc[PTS][2][NTP] = {};  // [pt][mt][nt]
        bf16x8 bh[NTP];
#pragma unroll
        for (int nt = 0; nt < NTP; ++nt) {
            size_t wi = ((size_t)((wv * NTW + ng + nt) * KC + 0) * 64 + lane) * 8;
            bh[nt] = *(const bf16x8*)&wbT[wi];
        }
#pragma unroll
        for (int ks = 0; ks < KC; ++ks) {
            bf16x8 bhn[NTP];
            if (ks + 1 < KC) {
#pragma unroll
                for (int nt = 0; nt < NTP; ++nt) {
                    size_t wi = ((size_t)((wv * NTW + ng + nt) * KC + (ks + 1)) * 64 + lane) * 8;
                    bhn[nt] = *(const bf16x8*)&wbT[wi];
                }
            }
            int slot = q * 16 + (ln ^ ((ks << 2) | q));
#pragma unroll
            for (int pt = 0; pt < PTS; ++pt)
#pragma unroll
                for (int mt = 0; mt < 2; ++mt) {
                    bf16x8 a = *(const bf16x8*)
                        &hfrag[(((pt * 2 + mt) * KC + ks) * 64 + slot) * 8];
#pragma unroll
                    for (int nt = 0; nt < NTP; ++nt)
                        acc[pt][mt][nt] = mfma16(a, bh[nt], acc[pt][mt][nt]);
                }
            if (ks + 1 < KC) {
#pragma unroll
                for (int nt = 0; nt < NTP; ++nt) bh[nt] = bhn[nt];
            }
        }
        // per-point max over 32 rows, bias+lrelu, store (frees accs)
#pragma unroll
        for (int pt = 0; pt < PTS; ++pt)
#pragma unroll
            for (int nt = 0; nt < NTP; ++nt) {
                int col = wv * (COUT / 4) + (ng + nt) * 16 + ln;
                float m = acc[pt][0][nt][0];
#pragma unroll
                for (int r = 1; r < 4; ++r) m = fmaxf(m, acc[pt][0][nt][r]);
#pragma unroll
                for (int r = 0; r < 4; ++r) m = fmaxf(m, acc[pt][1][nt][r]);
                m = fmaxf(m, __shfl_xor(m, 16));
                m = fmaxf(m, __shfl_xor(m, 32));
                if (q == 0) {
                    float v = m + bb[col];
                    v = v >= 0.f ? v : 0.2f * v;
                    if constexpr (OUTB)
                        ((u16*)outp)[(size_t)(p0 + pt) * COUT + col] = f2b(v);
                    else
                        ((float*)outp)[(size_t)(p0 + pt) * COUT + col] = v;
                }
            }
    }
}

// ---------------------------------------------------------------------------
// head123 (R7+R8 fusion): stage 1 = head1 (concat 704 -> 512, lrelu),
// bit-identical; 32x512 bf16 tile -> LDS Bs [32][520] (overlays AsH/AsL).
// Stage 2 = head_bf<512,256> body verbatim; its 32x256 bf16 output goes to
// LDS Bs2 [32][264] (overlays Bs after barrier) instead of HBM h2.
// Stage 3 = head_gemm3 body verbatim, wave 0 only (identical ks order and
// acc chains) -> final f32 out. Eliminates h1 (16MB W+R, R7) and h2
// (8MB W+R, R8) HBM round-trips + 2 launches. Output bit-identical.
// ---------------------------------------------------------------------------
__global__ __launch_bounds__(256) void head123(
    const float* __restrict__ x1, const float* __restrict__ x2,
    const u16* __restrict__ x3,
    const u16* __restrict__ wT1, const float* __restrict__ b1,
    const u16* __restrict__ wT2, const float* __restrict__ b2,
    const u16* __restrict__ wT3, const float* __restrict__ b3,
    float* __restrict__ out3)
{
    constexpr int KD = 704, KT = 352, SA = 360, SB = 520, SB3 = 264;
    __shared__ __align__(16) u16 lds[2 * 32 * SA];   // 46080 B
    u16* AsH = lds;
    u16* AsL = lds + 32 * SA;
    u16* Bs  = lds;                                  // stage-2 overlay [32][SB]
    u16* Bs2 = lds;                                  // stage-3 overlay [32][SB3]
    int row0 = blockIdx.x * 32;
    int tid = threadIdx.x, lane = tid & 63, wv = tid >> 6, ln = lane & 15, q = lane >> 4;

    f32x4 acc[2][8] = {};
    const int wbase = wv * 128;

    for (int ph = 0; ph < 2; ++ph) {
        if (ph) __syncthreads();
        for (int e = tid; e < 32 * 44; e += 256) {
            int r = e / 44, c8l = e % 44;
            int c = ph * KT + c8l * 8;
            int g = row0 + r;
            int a = r * SA + c8l * 8;
            if (c < 192) {
                const float* src = (c < 64) ? &x1[(size_t)g * 64 + c]
                                            : &x2[(size_t)g * 128 + (c - 64)];
                bf16x8 hv, lv;
#pragma unroll
                for (int jj = 0; jj < 8; ++jj) {
                    float v = src[jj];
                    u16 hi = f2b(v);
                    hv[jj] = hi;
                    lv[jj] = f2b(v - b2f(hi));
                }
                *(bf16x8*)&AsH[a] = hv;
                *(bf16x8*)&AsL[a] = lv;
            } else {
                *(bf16x8*)&AsH[a] = *(const bf16x8*)&x3[(size_t)g * 512 + (c - 192)];
                bf16x8 z = {0, 0, 0, 0, 0, 0, 0, 0};
                *(bf16x8*)&AsL[a] = z;
            }
        }
        __syncthreads();
        for (int ks = 0; ks < 11; ++ks) {
            int gk = ph * 11 + ks;
            bool t3 = (gk < 6);
            bf16x8 a0h = *(const bf16x8*)&AsH[(ln) * SA + ks * 32 + q * 8];
            bf16x8 a1h = *(const bf16x8*)&AsH[(16 + ln) * SA + ks * 32 + q * 8];
            bf16x8 a0l = *(const bf16x8*)&AsL[(ln) * SA + ks * 32 + q * 8];
            bf16x8 a1l = *(const bf16x8*)&AsL[(16 + ln) * SA + ks * 32 + q * 8];
#pragma unroll
            for (int nt = 0; nt < 8; ++nt) {
                size_t wi = (size_t)(wbase + nt * 16 + ln) * KD + gk * 32 + q * 8;
                bf16x8 bh = *(const bf16x8*)&wT1[wi];
                acc[0][nt] = mfma16(a0h, bh, acc[0][nt]);
                acc[1][nt] = mfma16(a1h, bh, acc[1][nt]);
                if (t3) {
                    acc[0][nt] = mfma16(a0l, bh, acc[0][nt]);
                    acc[1][nt] = mfma16(a1l, bh, acc[1][nt]);
                }
            }
        }
    }
    // stage-1 epilogue -> LDS exchange (bit-identical values to old h1)
    __syncthreads();   // all AsH/AsL reads done before overlay
#pragma unroll
    for (int nt = 0; nt < 8; ++nt) {
        int col = wbase + nt * 16 + ln;
        float bv = b1[col];
#pragma unroll
        for (int mt = 0; mt < 2; ++mt)
#pragma unroll
            for (int r = 0; r < 4; ++r) {
                float v = acc[mt][nt][r] + bv;
                v = v >= 0.f ? v : 0.2f * v;
                Bs[(mt * 16 + q * 4 + r) * SB + col] = f2b(v);
            }
    }
    __syncthreads();

    // stage 2: head_bf<512,256> body (verbatim indexing, SA -> SB)
    f32x4 acc2[2][4] = {};
    const int wbase2 = wv * 64;
    for (int ks = 0; ks < 16; ++ks) {
        bf16x8 a0 = *(const bf16x8*)&Bs[(ln) * SB + ks * 32 + q * 8];
        bf16x8 a1 = *(const bf16x8*)&Bs[(16 + ln) * SB + ks * 32 + q * 8];
#pragma unroll
        for (int nt = 0; nt < 4; ++nt) {
            size_t wi = (size_t)(wbase2 + nt * 16 + ln) * 512 + ks * 32 + q * 8;
            bf16x8 bh = *(const bf16x8*)&wT2[wi];
            acc2[0][nt] = mfma16(a0, bh, acc2[0][nt]);
            acc2[1][nt] = mfma16(a1, bh, acc2[1][nt]);
        }
    }
    // stage-2 epilogue -> LDS exchange Bs2 (bit-identical values to old h2)
    __syncthreads();   // all Bs reads done before overlay
#pragma unroll
    for (int nt = 0; nt < 4; ++nt) {
        int col = wbase2 + nt * 16 + ln;
        float bv = b2[col];
#pragma unroll
        for (int mt = 0; mt < 2; ++mt)
#pragma unroll
            for (int r = 0; r < 4; ++r) {
                float v = acc2[mt][nt][r] + bv;
                v = v >= 0.f ? v : 0.2f * v;
                Bs2[(mt * 16 + q * 4 + r) * SB3 + col] = f2b(v);
            }
    }
    __syncthreads();

    // stage 3: head_gemm3 body (verbatim ks order/acc chains), wave 0 only
    if (wv == 0) {
        f32x4 acc3[2] = {};
#pragma unroll
        for (int ks = 0; ks < 8; ++ks) {
            bf16x8 a0 = *(const bf16x8*)&Bs2[(ln) * SB3 + ks * 32 + q * 8];
            bf16x8 a1 = *(const bf16x8*)&Bs2[(16 + ln) * SB3 + ks * 32 + q * 8];
            size_t wi = (size_t)ln * 256 + ks * 32 + q * 8;
            bf16x8 bh = *(const bf16x8*)&wT3[wi];
            acc3[0] = mfma16(a0, bh, acc3[0]);
            acc3[1] = mfma16(a1, bh, acc3[1]);
        }
        if (ln < 12) {
            float bv = b3[ln];
#pragma unroll
            for (int mt = 0; mt < 2; ++mt)
#pragma unroll
                for (int r = 0; r < 4; ++r)
                    out3[(size_t)(row0 + mt * 16 + q * 4 + r) * 12 + ln] = acc3[mt][r] + bv;
        }
    }
}

// ---------------------------------------------------------------------------
// Workspace (peak 50,708,480 B = 48.4 MB):
//   [0,        2473984)  split weights
//   [2473984,  4571136)  idxb
//   [4571136,  8765440)  x1 f32      (pos4 256KB overlays head during
//                        prep+knn; x1 written after knn -> safe)
//   [8765440, 17154048)  x2 f32
//   [17154048,33931264)  Uf f32 (<=8MB) @ +0, Vb bf16 (<=4MB) @ +8MB
//   [33931264,50708480)  x3 bf16
// ---------------------------------------------------------------------------
extern "C" void kernel_launch(void* const* d_in, const int* in_sizes, int n_in,
                              void* d_out, int out_size, void* d_ws, size_t ws_size,
                              hipStream_t stream)
{
    (void)in_sizes; (void)n_in; (void)out_size; (void)ws_size;
    const float* x   = (const float*)d_in[0];
    const float* pos = (const float*)d_in[1];
    const float* w1a = (const float*)d_in[2];  const float* b1a = (const float*)d_in[3];
    const float* w1b = (const float*)d_in[4];  const float* b1b = (const float*)d_in[5];
    const float* w2a = (const float*)d_in[6];  const float* b2a = (const float*)d_in[7];
    const float* w2b = (const float*)d_in[8];  const float* b2b = (const float*)d_in[9];
    const float* w3a = (const float*)d_in[10]; const float* b3a = (const float*)d_in[11];
    const float* w3b = (const float*)d_in[12]; const float* b3b = (const float*)d_in[13];
    const float* wf1 = (const float*)d_in[14]; const float* bf1 = (const float*)d_in[15];
    const float* wf2 = (const float*)d_in[16]; const float* bf2 = (const float*)d_in[17];
    const float* wf3 = (const float*)d_in[18]; const float* bf3 = (const float*)d_in[19];

    char* ws = (char*)d_ws;
    u16* t1uv = (u16*)(ws + 0);
    u16* t2uv = (u16*)(ws + 16384);
    u16* t3uv = (u16*)(ws + 49152);
    u16* t1b  = (u16*)(ws + 180224);
    u16* t2b  = (u16*)(ws + 196608);
    u16* t3b  = (u16*)(ws + 229376);
    u16* tf1  = (u16*)(ws + 491520);
    u16* tf2  = (u16*)(ws + 1933312);
    u16* tf3  = (u16*)(ws + 2457600);
    int*   idxb = (int*)(ws + 2473984);
    float* x1 = (float*)(ws + 4571136);
    float* x2 = (float*)(ws + 8765440);
    float* Uf = (float*)(ws + 17154048);           // <= 8 MB (edge3)
    u16*   Vb = (u16*)(ws + 17154048 + 8388608);   // <= 4 MB (edge3)
    u16*   x3 = (u16*)(ws + 33931264);
    float4* pos4 = (float4*)(ws + 4571136);  // 256KB, dead after knn (x1 overlays)

    prep_weights<<<2480, 256, 0, stream>>>(w1a, w1b, w2a, w2b, w3a, w3b, wf1, wf2, wf3,
                                           pos, t1uv, t2uv, t3uv, t1b, t2b, t3b,
                                           tf1, tf2, tf3, pos4);
    knn_kernel<<<4096, 256, 0, stream>>>(pos4, idxb);
    uv_gemm<  3, 32, 128><<<512, 256, 0, stream>>>(x,  t1uv, b1a, Uf, Vb);
    edge_pool< 64,  64, false, 2, 1><<<8192, 256, 0, stream>>>(Uf, Vb, idxb, t1b, b1b, x1);
    uv_gemm< 64, 64, 128><<<512, 256, 0, stream>>>(x1, t2uv, b2a, Uf, Vb);
    edge_pool< 64, 128, false, 2, 2><<<8192, 256, 0, stream>>>(Uf, Vb, idxb, t2b, b2b, x2);
    uv_gemm<128, 128, 256><<<512, 256, 0, stream>>>(x2, t3uv, b3a, Uf, Vb);
    edge_pool<128, 512, true, 2, 2><<<8192, 256, 0, stream>>>(Uf, Vb, idxb, t3b, b3b, x3);
    head123<<<512, 256, 0, stream>>>(x1, x2, x3, tf1, bf1, tf2, bf2, tf3, bf3,
                                     (float*)d_out);
}

// Round 11
// 360.318 us; speedup vs baseline: 1.0666x; 1.0123x over previous
//
#include <hip/hip_runtime.h>

typedef unsigned short u16;
typedef unsigned int u32;
typedef unsigned long long u64;
typedef short bf16x8 __attribute__((ext_vector_type(8)));
typedef float f32x4 __attribute__((ext_vector_type(4)));
typedef u32 u32x4 __attribute__((ext_vector_type(4)));

__device__ __forceinline__ float b2f(u16 u) {
    return __uint_as_float(((u32)u) << 16);
}
__device__ __forceinline__ u16 f2b(float f) {  // RNE
    u32 u = __float_as_uint(f);
    u32 r = u + 0x7fffu + ((u >> 16) & 1u);
    return (u16)(r >> 16);
}
__device__ __forceinline__ f32x4 mfma16(bf16x8 a, bf16x8 b, f32x4 c) {
    return __builtin_amdgcn_mfma_f32_16x16x32_bf16(a, b, c, 0, 0, 0);
}

// ---------------------------------------------------------------------------
// prep: weights. seg -> W^T[n][k] row-major split bf16 (hi, lo planes).
// seg_bf -> MFMA B-fragment order: [tile][ks][lane][8]. seg_uv -> stacked
// [(Wa1-Wa2)^T ; Wa2^T]. R6: final segment builds pos4[m] = {x,y,z, sum(q^2)}
// with the EXACT __fmul_rn/__fadd_rn sequence knn used in-loop (bit-same).
// ---------------------------------------------------------------------------
template<int NP, int KP, int R, int C>
__device__ __forceinline__ bool seg(int t, int base, const float* src, u16* dst) {
    int r = t - base;
    if (r < 0) return true;
    constexpr int RNG = NP * KP;
    if (r >= RNG) return false;
    int n = r / KP, k = r - n * KP;
    float v = (k < R && n < C) ? src[k * C + n] : 0.f;
    u16 hi = f2b(v);
    dst[r] = hi;
    dst[RNG + r] = f2b(v - b2f(hi));
    return true;
}
template<int NP, int KP, int R, int C>
__device__ __forceinline__ bool seg_bf(int t, int base, const float* src, u16* dst) {
    int r = t - base;
    if (r < 0) return true;
    constexpr int RNG = NP * KP;
    if (r >= RNG) return false;
    constexpr int KC = KP / 32;
    int j = r & 7, s = r >> 3;
    int lanei = s & 63;
    int ks = (s >> 6) % KC, tile = (s >> 6) / KC;
    int n = tile * 16 + (lanei & 15);
    int k = ks * 32 + (lanei >> 4) * 8 + j;
    float v = (k < R && n < C) ? src[k * C + n] : 0.f;
    u16 hi = f2b(v);
    dst[r] = hi;
    dst[RNG + r] = f2b(v - b2f(hi));
    return true;
}
template<int CMID, int CIN, int KP>
__device__ __forceinline__ bool seg_uv(int t, int base, const float* wa, u16* dst) {
    int r = t - base;
    if (r < 0) return true;
    constexpr int RNG = 2 * CMID * KP;
    if (r >= RNG) return false;
    int n = r / KP, k = r - n * KP;
    float v = 0.f;
    if (k < CIN) {
        if (n < CMID) v = wa[k * CMID + n] - wa[(CIN + k) * CMID + n];
        else          v = wa[(CIN + k) * CMID + (n - CMID)];
    }
    u16 hi = f2b(v);
    dst[r] = hi;
    dst[RNG + r] = f2b(v - b2f(hi));
    return true;
}

__global__ __launch_bounds__(256) void prep_weights(
    const float* w1a, const float* w1b, const float* w2a, const float* w2b,
    const float* w3a, const float* w3b, const float* wf1, const float* wf2,
    const float* wf3, const float* pos,
    u16* t1uv, u16* t2uv, u16* t3uv, u16* t1b, u16* t2b, u16* t3b,
    u16* tf1, u16* tf2, u16* tf3, float4* pos4)
{
    int t = blockIdx.x * 256 + threadIdx.x;
    if (seg_uv< 64,   3,  32>(t,      0, w1a, t1uv)) return;
    if (seg_uv< 64,  64,  64>(t,   4096, w2a, t2uv)) return;
    if (seg_uv<128, 128, 128>(t,  12288, w3a, t3uv)) return;
    if (seg_bf< 64,  64,  64,  64>(t,  45056, w1b, t1b)) return;
    if (seg_bf<128,  64,  64, 128>(t,  49152, w2b, t2b)) return;
    if (seg_bf<512, 128, 128, 512>(t,  57344, w3b, t3b)) return;
    if (seg<512, 704, 704, 512>(t, 122880, wf1, tf1)) return;
    if (seg<256, 512, 512, 256>(t, 483328, wf2, tf2)) return;
    if (seg< 16, 256, 256,  12>(t, 614400, wf3, tf3)) return;
    int r = t - 618496;
    if (r >= 0 && r < 16384) {
        const float* q = pos + (size_t)r * 3;
        float q0 = q[0], q1 = q[1], q2 = q[2];
        float sqm = __fadd_rn(__fadd_rn(__fmul_rn(q0, q0), __fmul_rn(q1, q1)),
                              __fmul_rn(q2, q2));
        float4 v; v.x = q0; v.y = q1; v.z = q2; v.w = sqm;
        pos4[r] = v;
    }
}

// ---------------------------------------------------------------------------
// kNN: one WAVE per point. Key = 2^52 + ((orderable(d2) << 11) | idx) built
// via BIT-PACKING. fmin/fmax = exact lexicographic (d2, idx) compare.
// R6: pos as coalesced float4 {x,y,z,sq}. Phase 1: T = 32nd-smallest of
// lane-minima (R5 pairwise-tree lane-min + 64-lane bitonic).
// R10: Phase 2 compaction = per-lane count + shfl_up prefix SCAN + per-lane
// contiguous stores (replaces 32 SERIAL ballot+popc iterations). base is
// identical (sum of lane counts); candidate ORDER differs but the full sort
// makes placement irrelevant -> output bit-identical.
// R10: adaptive sort tier — base<=128 uses bitonic128 (2 regs/lane, ~45%
// fewer stages); else bitonic256. Both sort ALL candidates ascending; first
// 32 identical. Gate base>256 -> exact fallback (unchanged).
// ---------------------------------------------------------------------------
__device__ __forceinline__ void bitonic256(double v[4], int lane) {
#pragma unroll
    for (int k = 2; k <= 256; k <<= 1) {
#pragma unroll
        for (int j = k >> 1; j > 0; j >>= 1) {
            if (j >= 4) {
                int lj = j >> 2;
                bool upLane = ((lane & (k >> 2)) == 0);   // k>=8 here; r&k==0
                bool lowLane = ((lane & lj) == 0);
                bool keepMin = (upLane == lowLane);
#pragma unroll
                for (int r = 0; r < 4; ++r) {
                    double o = __shfl_xor(v[r], lj);
                    double mn = fmin(v[r], o), mx = fmax(v[r], o);
                    v[r] = keepMin ? mn : mx;
                }
            } else {
#pragma unroll
                for (int r = 0; r < 4; ++r) {
                    if ((r & j) == 0) {
                        int r2 = r | j;
                        bool up = (((lane * 4 + r) & k) == 0);
                        double mn = fmin(v[r], v[r2]), mx = fmax(v[r], v[r2]);
                        v[r] = up ? mn : mx;
                        v[r2] = up ? mx : mn;
                    }
                }
            }
        }
    }
}

__device__ __forceinline__ void bitonic128(double v[2], int lane) {
#pragma unroll
    for (int k = 2; k <= 128; k <<= 1) {
#pragma unroll
        for (int j = k >> 1; j > 0; j >>= 1) {
            if (j >= 2) {
                int lj = j >> 1;
                // i = lane*2+r; j>=2 -> i&j = (lane&lj) scaled; k>=2j>=4 ->
                // i&k = (lane & (k>>1)) scaled (r bit never reaches k)
                bool upLane = ((lane & (k >> 1)) == 0);
                bool lowLane = ((lane & lj) == 0);
                bool keepMin = (upLane == lowLane);
#pragma unroll
                for (int r = 0; r < 2; ++r) {
                    double o = __shfl_xor(v[r], lj);
                    double mn = fmin(v[r], o), mx = fmax(v[r], o);
                    v[r] = keepMin ? mn : mx;
                }
            } else {
                // j==1: intra-lane pair; k>=2 -> i&k independent of r
                bool up = (((lane * 2) & k) == 0);
                double mn = fmin(v[0], v[1]), mx = fmax(v[0], v[1]);
                v[0] = up ? mn : mx;
                v[1] = up ? mx : mn;
            }
        }
    }
}

__global__ __launch_bounds__(256) void knn_kernel(const float4* __restrict__ pos4,
                                                  int* __restrict__ idxout)
{
    int tid = threadIdx.x, lane = tid & 63, wv = tid >> 6;
    int p = blockIdx.x * 4 + wv;
    int b = p >> 11, n = p & 2047;
    __shared__ double cand[4][256];
    const float4* pb4 = pos4 + (size_t)b * 2048;
    float4 pn = pb4[n];
    float pn0 = pn.x, pn1 = pn.y, pn2 = pn.z, sqn = pn.w;
    double kd[32];
#pragma unroll
    for (int j = 0; j < 32; ++j) {
        int m = lane + j * 64;
        float4 qm = pb4[m];
        float dot = __fadd_rn(__fadd_rn(__fmul_rn(pn0, qm.x), __fmul_rn(pn1, qm.y)),
                              __fmul_rn(pn2, qm.z));
        float d2 = __fadd_rn(__fsub_rn(sqn, __fmul_rn(2.0f, dot)), qm.w);
        u32 u = __float_as_uint(d2);
        u = (u & 0x80000000u) ? ~u : (u | 0x80000000u);  // orderable
        u32 lo = (u << 11) | (u32)m;
        u32 hi = 0x43300000u | (u >> 21);
        kd[j] = __hiloint2double((int)hi, (int)lo);
    }

    // Phase 1: lane-minima (pairwise tree), 64-lane bitonic, T = 32nd smallest.
    double tmin[16];
#pragma unroll
    for (int j = 0; j < 16; ++j) tmin[j] = fmin(kd[j], kd[j + 16]);
#pragma unroll
    for (int j = 0; j < 8; ++j) tmin[j] = fmin(tmin[j], tmin[j + 8]);
#pragma unroll
    for (int j = 0; j < 4; ++j) tmin[j] = fmin(tmin[j], tmin[j + 4]);
    double lmin = fmin(fmin(tmin[0], tmin[2]), fmin(tmin[1], tmin[3]));
    double v = lmin;
#pragma unroll
    for (int k = 2; k <= 64; k <<= 1) {
#pragma unroll
        for (int j2 = k >> 1; j2 > 0; j2 >>= 1) {
            double o = __shfl_xor(v, j2);
            bool up = ((lane & k) == 0);
            bool low = ((lane & j2) == 0);
            double mn = fmin(v, o), mx = fmax(v, o);
            v = (up == low) ? mn : mx;
        }
    }
    double T = __shfl(v, 31);

    // Phase 2 (R10): per-lane count + prefix scan + per-lane compaction.
    int c = 0;
#pragma unroll
    for (int j = 0; j < 32; ++j) c += (kd[j] <= T) ? 1 : 0;
    int s = c;
#pragma unroll
    for (int off = 1; off < 64; off <<= 1) {
        int t = __shfl_up(s, off);
        if (lane >= off) s += t;
    }
    int base = __shfl(s, 63);
    int slot = s - c;  // exclusive prefix: this lane's first slot

#pragma unroll
    for (int s4 = 0; s4 < 4; ++s4) cand[wv][lane + s4 * 64] = 1e300;
    // wave-synchronous: pad stores precede compaction stores in instr order
#pragma unroll
    for (int j = 0; j < 32; ++j) {
        if (kd[j] <= T) {
            if (slot < 256) cand[wv][slot] = kd[j];
            ++slot;
        }
    }

    if (base <= 128) {   // base >= 32 guaranteed (32 lane-minima <= T)
        double kc[2];
#pragma unroll
        for (int j = 0; j < 2; ++j) kc[j] = cand[wv][lane * 2 + j];
        bitonic128(kc, lane);
        if (lane < 16) {
            int2 w;
            w.x = __double2loint(kc[0]) & 2047;
            w.y = __double2loint(kc[1]) & 2047;
            *(int2*)&idxout[(size_t)p * 32 + lane * 2] = w;
        }
    } else if (base <= 256) {
        double kc[4];
#pragma unroll
        for (int j = 0; j < 4; ++j) kc[j] = cand[wv][lane * 4 + j];
        bitonic256(kc, lane);
        if (lane < 8) {
            int4 w;
            w.x = __double2loint(kc[0]) & 2047;
            w.y = __double2loint(kc[1]) & 2047;
            w.z = __double2loint(kc[2]) & 2047;
            w.w = __double2loint(kc[3]) & 2047;
            *(int4*)&idxout[(size_t)p * 32 + lane * 4] = w;
        }
    } else {
        // Fallback: exact full-register selection (R9 path).
        double last = -1.0;
        for (int it = 0; it < 32; ++it) {
            double lm0 = 1e300, lm1 = 1e300;
#pragma unroll
            for (int j = 0; j < 32; j += 2) {
                double t0 = kd[j], t1 = kd[j + 1];
                lm0 = fmin(lm0, (t0 > last) ? t0 : 1e300);
                lm1 = fmin(lm1, (t1 > last) ? t1 : 1e300);
            }
            double lm = fmin(lm0, lm1);
#pragma unroll
            for (int off = 32; off; off >>= 1)
                lm = fmin(lm, __shfl_xor(lm, off));
            if (lane == 0) idxout[(size_t)p * 32 + it] = __double2loint(lm) & 2047;
            last = lm;
        }
    }
}

// ---------------------------------------------------------------------------
// UV GEMM: U[n][c] = x@(Wa1-Wa2)+ba  (f32, exact, read once per point);
//          V[n][c] = x@Wa2           (bf16, gathered 32x -> half traffic).
// A f32 -> split LDS, 3-term MFMA vs split weights (defines U/V precision).
// ---------------------------------------------------------------------------
template<int K, int KP, int N2>
__global__ __launch_bounds__(256) void uv_gemm(
    const float* __restrict__ xin, const u16* __restrict__ wT,
    const float* __restrict__ ba, float* __restrict__ Uf, u16* __restrict__ Vb)
{
    constexpr int SA = KP + 8;
    constexpr int WSZ = N2 * KP;
    constexpr int CMID = N2 / 2;
    __shared__ __align__(16) u16 AsH[32 * SA];
    __shared__ __align__(16) u16 AsL[32 * SA];
    int row0 = blockIdx.x * 32;
    int tid = threadIdx.x, lane = tid & 63, wv = tid >> 6, ln = lane & 15, q = lane >> 4;

    for (int e = tid; e < 32 * (KP / 8); e += 256) {
        int r = e / (KP / 8), c0 = (e % (KP / 8)) * 8;
        bf16x8 hv, lv;
#pragma unroll
        for (int jj = 0; jj < 8; ++jj) {
            int c = c0 + jj;
            float v = (c < K) ? xin[(size_t)(row0 + r) * K + c] : 0.f;
            u16 hi = f2b(v);
            hv[jj] = hi;
            lv[jj] = f2b(v - b2f(hi));
        }
        *(bf16x8*)&AsH[r * SA + c0] = hv;
        *(bf16x8*)&AsL[r * SA + c0] = lv;
    }
    __syncthreads();

    constexpr int NT = N2 / 64;
    f32x4 acc[2][NT] = {};
    const int wbase = wv * (N2 / 4);
#pragma unroll
    for (int ks = 0; ks < KP / 32; ++ks) {
        bf16x8 a0h = *(const bf16x8*)&AsH[(ln) * SA + ks * 32 + q * 8];
        bf16x8 a1h = *(const bf16x8*)&AsH[(16 + ln) * SA + ks * 32 + q * 8];
        bf16x8 a0l = *(const bf16x8*)&AsL[(ln) * SA + ks * 32 + q * 8];
        bf16x8 a1l = *(const bf16x8*)&AsL[(16 + ln) * SA + ks * 32 + q * 8];
#pragma unroll
        for (int nt = 0; nt < NT; ++nt) {
            size_t wi = (size_t)(wbase + nt * 16 + ln) * KP + ks * 32 + q * 8;
            bf16x8 bh = *(const bf16x8*)&wT[wi];
            bf16x8 bl = *(const bf16x8*)&wT[WSZ + wi];
            acc[0][nt] = mfma16(a0h, bh, acc[0][nt]);
            acc[0][nt] = mfma16(a0h, bl, acc[0][nt]);
            acc[0][nt] = mfma16(a0l, bh, acc[0][nt]);
            acc[1][nt] = mfma16(a1h, bh, acc[1][nt]);
            acc[1][nt] = mfma16(a1h, bl, acc[1][nt]);
            acc[1][nt] = mfma16(a1l, bh, acc[1][nt]);
        }
    }
#pragma unroll
    for (int nt = 0; nt < NT; ++nt) {
        int col = wbase + nt * 16 + ln;
#pragma unroll
        for (int mt = 0; mt < 2; ++mt)
#pragma unroll
            for (int r = 0; r < 4; ++r) {
                size_t row = (size_t)(row0 + mt * 16 + q * 4 + r);
                if (col < CMID)
                    Uf[row * CMID + col] = acc[mt][nt][r] + ba[col];
                else
                    Vb[row * CMID + (col - CMID)] = f2b(acc[mt][nt][r]);
            }
    }
}

// ---------------------------------------------------------------------------
// Edge pool — R2-PROVEN config (89.8us R10-measured; R16 laws: PTS=2,
// (256,4), NTP<=2, 1-term Wb). R3/R4 register-hoist REFUTED. R1: ks unroll +
// 1-deep weight prefetch; conversion unroll.
// R9: XCD-aware chunked blockIdx swizzle (one batch per XCD) — FETCH_SIZE
// 21.5 -> 7.7MB measured. Bijective (nwg%8==0).
// Tripwire: WRITE_SIZE ~= output, VGPR=64, FETCH ~7.7MB.
// ---------------------------------------------------------------------------
template<int CMID, int COUT, bool OUTB, int PTS, int NTP>
__global__ __launch_bounds__(256, 4) void edge_pool(
    const float* __restrict__ Uf, const u16* __restrict__ Vb,
    const int* __restrict__ idx,
    const u16* __restrict__ wbT, const float* __restrict__ bb,
    void* __restrict__ outp)
{
    constexpr int KC = CMID / 32;
    constexpr int C8 = CMID / 8;
    constexpr int NTW = COUT / 64;
    constexpr int CITER = PTS * 32 * C8 / 256;  // exact (divisible)
    __shared__ __align__(16) u16 hfrag[PTS * 2 * KC * 512];
    __shared__ int nbr[PTS * 32];

    int tid = threadIdx.x, lane = tid & 63, wv = tid >> 6, ln = lane & 15, q = lane >> 4;
    int cpx = gridDim.x >> 3;
    int wgid = (blockIdx.x & 7) * cpx + (blockIdx.x >> 3);  // batch-per-XCD
    int p0 = wgid * PTS;

    if (tid < PTS * 32) {
        int pt = tid >> 5, kk = tid & 31;
        int p = p0 + pt;
        nbr[tid] = ((p >> 11) << 11) + (idx[(size_t)p * 32 + kk] & 2047);
    }
    __syncthreads();

    // build h in swizzled fragment order (packed conversion), unrolled so the
    // per-iteration gather/U loads issue back-to-back and pipeline
#pragma unroll
    for (int e0 = 0; e0 < CITER; ++e0) {
        int e = tid + e0 * 256;
        int pt = e / (32 * C8), rem = e % (32 * C8), r = rem / C8, c8 = rem % C8;
        const float* U = &Uf[(size_t)(p0 + pt) * CMID + c8 * 8];
        bf16x8 vb = *(const bf16x8*)&Vb[(size_t)nbr[pt * 32 + r] * CMID + c8 * 8];
        u32x4 hq;
#pragma unroll
        for (int jj = 0; jj < 4; ++jj) {
            float f0 = U[2 * jj]     + b2f((u16)vb[2 * jj]);
            float f1 = U[2 * jj + 1] + b2f((u16)vb[2 * jj + 1]);
            f0 = f0 >= 0.f ? f0 : 0.2f * f0;
            f1 = f1 >= 0.f ? f1 : 0.2f * f1;
            u32 a = __float_as_uint(f0) + 0x8000u;
            u32 b = __float_as_uint(f1) + 0x8000u;
            hq[jj] = __builtin_amdgcn_perm(b, a, 0x07060302u);  // hi16(f1)<<16|hi16(f0)
        }
        int mt = r >> 4, lnr = r & 15, ks = c8 >> 2, qq = c8 & 3;
        int slot = qq * 16 + (lnr ^ ((ks << 2) | qq));
        *(u32x4*)&hfrag[(((pt * 2 + mt) * KC + ks) * 64 + slot) * 8] = hq;
    }
    __syncthreads();

    for (int ng = 0; ng < NTW; ng += NTP) {
        f32x4 acc[PTS][2][NTP] = {};  // [pt][mt][nt]
        bf16x8 bh[NTP];
#pragma unroll
        for (int nt = 0; nt < NTP; ++nt) {
            size_t wi = ((size_t)((wv * NTW + ng + nt) * KC + 0) * 64 + lane) * 8;
            bh[nt] = *(const bf16x8*)&wbT[wi];
        }
#pragma unroll
        for (int ks = 0; ks < KC; ++ks) {
            bf16x8 bhn[NTP];
            if (ks + 1 < KC) {
#pragma unroll
                for (int nt = 0; nt < NTP; ++nt) {
                    size_t wi = ((size_t)((wv * NTW + ng + nt) * KC + (ks + 1)) * 64 + lane) * 8;
                    bhn[nt] = *(const bf16x8*)&wbT[wi];
                }
            }
            int slot = q * 16 + (ln ^ ((ks << 2) | q));
#pragma unroll
            for (int pt = 0; pt < PTS; ++pt)
#pragma unroll
                for (int mt = 0; mt < 2; ++mt) {
                    bf16x8 a = *(const bf16x8*)
                        &hfrag[(((pt * 2 + mt) * KC + ks) * 64 + slot) * 8];
#pragma unroll
                    for (int nt = 0; nt < NTP; ++nt)
                        acc[pt][mt][nt] = mfma16(a, bh[nt], acc[pt][mt][nt]);
                }
            if (ks + 1 < KC) {
#pragma unroll
                for (int nt = 0; nt < NTP; ++nt) bh[nt] = bhn[nt];
            }
        }
        // per-point max over 32 rows, bias+lrelu, store (frees accs)
#pragma unroll
        for (int pt = 0; pt < PTS; ++pt)
#pragma unroll
            for (int nt = 0; nt < NTP; ++nt) {
                int col = wv * (COUT / 4) + (ng + nt) * 16 + ln;
                float m = acc[pt][0][nt][0];
#pragma unroll
                for (int r = 1; r < 4; ++r) m = fmaxf(m, acc[pt][0][nt][r]);
#pragma unroll
                for (int r = 0; r < 4; ++r) m = fmaxf(m, acc[pt][1][nt][r]);
                m = fmaxf(m, __shfl_xor(m, 16));
                m = fmaxf(m, __shfl_xor(m, 32));
                if (q == 0) {
                    float v = m + bb[col];
                    v = v >= 0.f ? v : 0.2f * v;
                    if constexpr (OUTB)
                        ((u16*)outp)[(size_t)(p0 + pt) * COUT + col] = f2b(v);
                    else
                        ((float*)outp)[(size_t)(p0 + pt) * COUT + col] = v;
                }
            }
    }
}

// ---------------------------------------------------------------------------
// head123 (R7+R8 fusion): stage 1 = head1 (concat 704 -> 512, lrelu),
// bit-identical; 32x512 bf16 tile -> LDS Bs [32][520] (overlays AsH/AsL).
// Stage 2 = head_bf<512,256> body verbatim; its 32x256 bf16 output goes to
// LDS Bs2 [32][264] (overlays Bs after barrier) instead of HBM h2.
// Stage 3 = head_gemm3 body verbatim, wave 0 only (identical ks order and
// acc chains) -> final f32 out. Eliminates h1 (16MB W+R, R7) and h2
// (8MB W+R, R8) HBM round-trips + 2 launches. Output bit-identical.
// ---------------------------------------------------------------------------
__global__ __launch_bounds__(256) void head123(
    const float* __restrict__ x1, const float* __restrict__ x2,
    const u16* __restrict__ x3,
    const u16* __restrict__ wT1, const float* __restrict__ b1,
    const u16* __restrict__ wT2, const float* __restrict__ b2,
    const u16* __restrict__ wT3, const float* __restrict__ b3,
    float* __restrict__ out3)
{
    constexpr int KD = 704, KT = 352, SA = 360, SB = 520, SB3 = 264;
    __shared__ __align__(16) u16 lds[2 * 32 * SA];   // 46080 B
    u16* AsH = lds;
    u16* AsL = lds + 32 * SA;
    u16* Bs  = lds;                                  // stage-2 overlay [32][SB]
    u16* Bs2 = lds;                                  // stage-3 overlay [32][SB3]
    int row0 = blockIdx.x * 32;
    int tid = threadIdx.x, lane = tid & 63, wv = tid >> 6, ln = lane & 15, q = lane >> 4;

    f32x4 acc[2][8] = {};
    const int wbase = wv * 128;

    for (int ph = 0; ph < 2; ++ph) {
        if (ph) __syncthreads();
        for (int e = tid; e < 32 * 44; e += 256) {
            int r = e / 44, c8l = e % 44;
            int c = ph * KT + c8l * 8;
            int g = row0 + r;
            int a = r * SA + c8l * 8;
            if (c < 192) {
                const float* src = (c < 64) ? &x1[(size_t)g * 64 + c]
                                            : &x2[(size_t)g * 128 + (c - 64)];
                bf16x8 hv, lv;
#pragma unroll
                for (int jj = 0; jj < 8; ++jj) {
                    float v = src[jj];
                    u16 hi = f2b(v);
                    hv[jj] = hi;
                    lv[jj] = f2b(v - b2f(hi));
                }
                *(bf16x8*)&AsH[a] = hv;
                *(bf16x8*)&AsL[a] = lv;
            } else {
                *(bf16x8*)&AsH[a] = *(const bf16x8*)&x3[(size_t)g * 512 + (c - 192)];
                bf16x8 z = {0, 0, 0, 0, 0, 0, 0, 0};
                *(bf16x8*)&AsL[a] = z;
            }
        }
        __syncthreads();
        for (int ks = 0; ks < 11; ++ks) {
            int gk = ph * 11 + ks;
            bool t3 = (gk < 6);
            bf16x8 a0h = *(const bf16x8*)&AsH[(ln) * SA + ks * 32 + q * 8];
            bf16x8 a1h = *(const bf16x8*)&AsH[(16 + ln) * SA + ks * 32 + q * 8];
            bf16x8 a0l = *(const bf16x8*)&AsL[(ln) * SA + ks * 32 + q * 8];
            bf16x8 a1l = *(const bf16x8*)&AsL[(16 + ln) * SA + ks * 32 + q * 8];
#pragma unroll
            for (int nt = 0; nt < 8; ++nt) {
                size_t wi = (size_t)(wbase + nt * 16 + ln) * KD + gk * 32 + q * 8;
                bf16x8 bh = *(const bf16x8*)&wT1[wi];
                acc[0][nt] = mfma16(a0h, bh, acc[0][nt]);
                acc[1][nt] = mfma16(a1h, bh, acc[1][nt]);
                if (t3) {
                    acc[0][nt] = mfma16(a0l, bh, acc[0][nt]);
                    acc[1][nt] = mfma16(a1l, bh, acc[1][nt]);
                }
            }
        }
    }
    // stage-1 epilogue -> LDS exchange (bit-identical values to old h1)
    __syncthreads();   // all AsH/AsL reads done before overlay
#pragma unroll
    for (int nt = 0; nt < 8; ++nt) {
        int col = wbase + nt * 16 + ln;
        float bv = b1[col];
#pragma unroll
        for (int mt = 0; mt < 2; ++mt)
#pragma unroll
            for (int r = 0; r < 4; ++r) {
                float v = acc[mt][nt][r] + bv;
                v = v >= 0.f ? v : 0.2f * v;
                Bs[(mt * 16 + q * 4 + r) * SB + col] = f2b(v);
            }
    }
    __syncthreads();

    // stage 2: head_bf<512,256> body (verbatim indexing, SA -> SB)
    f32x4 acc2[2][4] = {};
    const int wbase2 = wv * 64;
    for (int ks = 0; ks < 16; ++ks) {
        bf16x8 a0 = *(const bf16x8*)&Bs[(ln) * SB + ks * 32 + q * 8];
        bf16x8 a1 = *(const bf16x8*)&Bs[(16 + ln) * SB + ks * 32 + q * 8];
#pragma unroll
        for (int nt = 0; nt < 4; ++nt) {
            size_t wi = (size_t)(wbase2 + nt * 16 + ln) * 512 + ks * 32 + q * 8;
            bf16x8 bh = *(const bf16x8*)&wT2[wi];
            acc2[0][nt] = mfma16(a0, bh, acc2[0][nt]);
            acc2[1][nt] = mfma16(a1, bh, acc2[1][nt]);
        }
    }
    // stage-2 epilogue -> LDS exchange Bs2 (bit-identical values to old h2)
    __syncthreads();   // all Bs reads done before overlay
#pragma unroll
    for (int nt = 0; nt < 4; ++nt) {
        int col = wbase2 + nt * 16 + ln;
        float bv = b2[col];
#pragma unroll
        for (int mt = 0; mt < 2; ++mt)
#pragma unroll
            for (int r = 0; r < 4; ++r) {
                float v = acc2[mt][nt][r] + bv;
                v = v >= 0.f ? v : 0.2f * v;
                Bs2[(mt * 16 + q * 4 + r) * SB3 + col] = f2b(v);
            }
    }
    __syncthreads();

    // stage 3: head_gemm3 body (verbatim ks order/acc chains), wave 0 only
    if (wv == 0) {
        f32x4 acc3[2] = {};
#pragma unroll
        for (int ks = 0; ks < 8; ++ks) {
            bf16x8 a0 = *(const bf16x8*)&Bs2[(ln) * SB3 + ks * 32 + q * 8];
            bf16x8 a1 = *(const bf16x8*)&Bs2[(16 + ln) * SB3 + ks * 32 + q * 8];
            size_t wi = (size_t)ln * 256 + ks * 32 + q * 8;
            bf16x8 bh = *(const bf16x8*)&wT3[wi];
            acc3[0] = mfma16(a0, bh, acc3[0]);
            acc3[1] = mfma16(a1, bh, acc3[1]);
        }
        if (ln < 12) {
            float bv = b3[ln];
#pragma unroll
            for (int mt = 0; mt < 2; ++mt)
#pragma unroll
                for (int r = 0; r < 4; ++r)
                    out3[(size_t)(row0 + mt * 16 + q * 4 + r) * 12 + ln] = acc3[mt][r] + bv;
        }
    }
}

// ---------------------------------------------------------------------------
// Workspace (peak 50,708,480 B = 48.4 MB):
//   [0,        2473984)  split weights
//   [2473984,  4571136)  idxb
//   [4571136,  8765440)  x1 f32      (pos4 256KB overlays head during
//                        prep+knn; x1 written after knn -> safe)
//   [8765440, 17154048)  x2 f32
//   [17154048,33931264)  Uf f32 (<=8MB) @ +0, Vb bf16 (<=4MB) @ +8MB
//   [33931264,50708480)  x3 bf16
// ---------------------------------------------------------------------------
extern "C" void kernel_launch(void* const* d_in, const int* in_sizes, int n_in,
                              void* d_out, int out_size, void* d_ws, size_t ws_size,
                              hipStream_t stream)
{
    (void)in_sizes; (void)n_in; (void)out_size; (void)ws_size;
    const float* x   = (const float*)d_in[0];
    const float* pos = (const float*)d_in[1];
    const float* w1a = (const float*)d_in[2];  const float* b1a = (const float*)d_in[3];
    const float* w1b = (const float*)d_in[4];  const float* b1b = (const float*)d_in[5];
    const float* w2a = (const float*)d_in[6];  const float* b2a = (const float*)d_in[7];
    const float* w2b = (const float*)d_in[8];  const float* b2b = (const float*)d_in[9];
    const float* w3a = (const float*)d_in[10]; const float* b3a = (const float*)d_in[11];
    const float* w3b = (const float*)d_in[12]; const float* b3b = (const float*)d_in[13];
    const float* wf1 = (const float*)d_in[14]; const float* bf1 = (const float*)d_in[15];
    const float* wf2 = (const float*)d_in[16]; const float* bf2 = (const float*)d_in[17];
    const float* wf3 = (const float*)d_in[18]; const float* bf3 = (const float*)d_in[19];

    char* ws = (char*)d_ws;
    u16* t1uv = (u16*)(ws + 0);
    u16* t2uv = (u16*)(ws + 16384);
    u16* t3uv = (u16*)(ws + 49152);
    u16* t1b  = (u16*)(ws + 180224);
    u16* t2b  = (u16*)(ws + 196608);
    u16* t3b  = (u16*)(ws + 229376);
    u16* tf1  = (u16*)(ws + 491520);
    u16* tf2  = (u16*)(ws + 1933312);
    u16* tf3  = (u16*)(ws + 2457600);
    int*   idxb = (int*)(ws + 2473984);
    float* x1 = (float*)(ws + 4571136);
    float* x2 = (float*)(ws + 8765440);
    float* Uf = (float*)(ws + 17154048);           // <= 8 MB (edge3)
    u16*   Vb = (u16*)(ws + 17154048 + 8388608);   // <= 4 MB (edge3)
    u16*   x3 = (u16*)(ws + 33931264);
    float4* pos4 = (float4*)(ws + 4571136);  // 256KB, dead after knn (x1 overlays)

    prep_weights<<<2480, 256, 0, stream>>>(w1a, w1b, w2a, w2b, w3a, w3b, wf1, wf2, wf3,
                                           pos, t1uv, t2uv, t3uv, t1b, t2b, t3b,
                                           tf1, tf2, tf3, pos4);
    knn_kernel<<<4096, 256, 0, stream>>>(pos4, idxb);
    uv_gemm<  3, 32, 128><<<512, 256, 0, stream>>>(x,  t1uv, b1a, Uf, Vb);
    edge_pool< 64,  64, false, 2, 1><<<8192, 256, 0, stream>>>(Uf, Vb, idxb, t1b, b1b, x1);
    uv_gemm< 64, 64, 128><<<512, 256, 0, stream>>>(x1, t2uv, b2a, Uf, Vb);
    edge_pool< 64, 128, false, 2, 2><<<8192, 256, 0, stream>>>(Uf, Vb, idxb, t2b, b2b, x2);
    uv_gemm<128, 128, 256><<<512, 256, 0, stream>>>(x2, t3uv, b3a, Uf, Vb);
    edge_pool<128, 512, true, 2, 2><<<8192, 256, 0, stream>>>(Uf, Vb, idxb, t3b, b3b, x3);
    head123<<<512, 256, 0, stream>>>(x1, x2, x3, tf1, bf1, tf2, bf2, tf3, bf3,
                                     (float*)d_out);
}

// Round 13
// 357.768 us; speedup vs baseline: 1.0742x; 1.0071x over previous
//
#include <hip/hip_runtime.h>

typedef unsigned short u16;
typedef unsigned int u32;
typedef unsigned long long u64;
typedef short bf16x8 __attribute__((ext_vector_type(8)));
typedef float f32x4 __attribute__((ext_vector_type(4)));
typedef u32 u32x4 __attribute__((ext_vector_type(4)));

__device__ __forceinline__ float b2f(u16 u) {
    return __uint_as_float(((u32)u) << 16);
}
__device__ __forceinline__ u16 f2b(float f) {  // RNE
    u32 u = __float_as_uint(f);
    u32 r = u + 0x7fffu + ((u >> 16) & 1u);
    return (u16)(r >> 16);
}
__device__ __forceinline__ f32x4 mfma16(bf16x8 a, bf16x8 b, f32x4 c) {
    return __builtin_amdgcn_mfma_f32_16x16x32_bf16(a, b, c, 0, 0, 0);
}

// ---------------------------------------------------------------------------
// prep: weights. seg -> W^T[n][k] row-major split bf16 (hi, lo planes).
// seg_bf -> MFMA B-fragment order: [tile][ks][lane][8]. seg_uv -> stacked
// [(Wa1-Wa2)^T ; Wa2^T]. R6: final segment builds pos4[m] = {x,y,z, sum(q^2)}
// with the EXACT __fmul_rn/__fadd_rn sequence knn used in-loop (bit-same).
// ---------------------------------------------------------------------------
template<int NP, int KP, int R, int C>
__device__ __forceinline__ bool seg(int t, int base, const float* src, u16* dst) {
    int r = t - base;
    if (r < 0) return true;
    constexpr int RNG = NP * KP;
    if (r >= RNG) return false;
    int n = r / KP, k = r - n * KP;
    float v = (k < R && n < C) ? src[k * C + n] : 0.f;
    u16 hi = f2b(v);
    dst[r] = hi;
    dst[RNG + r] = f2b(v - b2f(hi));
    return true;
}
template<int NP, int KP, int R, int C>
__device__ __forceinline__ bool seg_bf(int t, int base, const float* src, u16* dst) {
    int r = t - base;
    if (r < 0) return true;
    constexpr int RNG = NP * KP;
    if (r >= RNG) return false;
    constexpr int KC = KP / 32;
    int j = r & 7, s = r >> 3;
    int lanei = s & 63;
    int ks = (s >> 6) % KC, tile = (s >> 6) / KC;
    int n = tile * 16 + (lanei & 15);
    int k = ks * 32 + (lanei >> 4) * 8 + j;
    float v = (k < R && n < C) ? src[k * C + n] : 0.f;
    u16 hi = f2b(v);
    dst[r] = hi;
    dst[RNG + r] = f2b(v - b2f(hi));
    return true;
}
template<int CMID, int CIN, int KP>
__device__ __forceinline__ bool seg_uv(int t, int base, const float* wa, u16* dst) {
    int r = t - base;
    if (r < 0) return true;
    constexpr int RNG = 2 * CMID * KP;
    if (r >= RNG) return false;
    int n = r / KP, k = r - n * KP;
    float v = 0.f;
    if (k < CIN) {
        if (n < CMID) v = wa[k * CMID + n] - wa[(CIN + k) * CMID + n];
        else          v = wa[(CIN + k) * CMID + (n - CMID)];
    }
    u16 hi = f2b(v);
    dst[r] = hi;
    dst[RNG + r] = f2b(v - b2f(hi));
    return true;
}

__global__ __launch_bounds__(256) void prep_weights(
    const float* w1a, const float* w1b, const float* w2a, const float* w2b,
    const float* w3a, const float* w3b, const float* wf1, const float* wf2,
    const float* wf3, const float* pos,
    u16* t1uv, u16* t2uv, u16* t3uv, u16* t1b, u16* t2b, u16* t3b,
    u16* tf1, u16* tf2, u16* tf3, float4* pos4)
{
    int t = blockIdx.x * 256 + threadIdx.x;
    if (seg_uv< 64,   3,  32>(t,      0, w1a, t1uv)) return;
    if (seg_uv< 64,  64,  64>(t,   4096, w2a, t2uv)) return;
    if (seg_uv<128, 128, 128>(t,  12288, w3a, t3uv)) return;
    if (seg_bf< 64,  64,  64,  64>(t,  45056, w1b, t1b)) return;
    if (seg_bf<128,  64,  64, 128>(t,  49152, w2b, t2b)) return;
    if (seg_bf<512, 128, 128, 512>(t,  57344, w3b, t3b)) return;
    if (seg<512, 704, 704, 512>(t, 122880, wf1, tf1)) return;
    if (seg<256, 512, 512, 256>(t, 483328, wf2, tf2)) return;
    if (seg< 16, 256, 256,  12>(t, 614400, wf3, tf3)) return;
    int r = t - 618496;
    if (r >= 0 && r < 16384) {
        const float* q = pos + (size_t)r * 3;
        float q0 = q[0], q1 = q[1], q2 = q[2];
        float sqm = __fadd_rn(__fadd_rn(__fmul_rn(q0, q0), __fmul_rn(q1, q1)),
                              __fmul_rn(q2, q2));
        float4 v; v.x = q0; v.y = q1; v.z = q2; v.w = sqm;
        pos4[r] = v;
    }
}

// ---------------------------------------------------------------------------
// kNN: one WAVE per point. Key = 2^52 + ((orderable(d2) << 11) | idx) built
// via BIT-PACKING. fmin/fmax = exact lexicographic (d2, idx) compare.
// R6: pos as coalesced float4 {x,y,z,sq}. Phase 1: T = 32nd-smallest of
// lane-minima (R5 pairwise-tree lane-min + 64-lane bitonic).
// R10: Phase 2 compaction = per-lane count + shfl_up prefix SCAN + per-lane
// contiguous stores. base identical; candidate order irrelevant (full sort).
// R10: adaptive sort tier — base<=128 -> bitonic128, else bitonic256.
// Gate base>256 -> exact fallback (unchanged).
// ---------------------------------------------------------------------------
__device__ __forceinline__ void bitonic256(double v[4], int lane) {
#pragma unroll
    for (int k = 2; k <= 256; k <<= 1) {
#pragma unroll
        for (int j = k >> 1; j > 0; j >>= 1) {
            if (j >= 4) {
                int lj = j >> 2;
                bool upLane = ((lane & (k >> 2)) == 0);   // k>=8 here; r&k==0
                bool lowLane = ((lane & lj) == 0);
                bool keepMin = (upLane == lowLane);
#pragma unroll
                for (int r = 0; r < 4; ++r) {
                    double o = __shfl_xor(v[r], lj);
                    double mn = fmin(v[r], o), mx = fmax(v[r], o);
                    v[r] = keepMin ? mn : mx;
                }
            } else {
#pragma unroll
                for (int r = 0; r < 4; ++r) {
                    if ((r & j) == 0) {
                        int r2 = r | j;
                        bool up = (((lane * 4 + r) & k) == 0);
                        double mn = fmin(v[r], v[r2]), mx = fmax(v[r], v[r2]);
                        v[r] = up ? mn : mx;
                        v[r2] = up ? mx : mn;
                    }
                }
            }
        }
    }
}

__device__ __forceinline__ void bitonic128(double v[2], int lane) {
#pragma unroll
    for (int k = 2; k <= 128; k <<= 1) {
#pragma unroll
        for (int j = k >> 1; j > 0; j >>= 1) {
            if (j >= 2) {
                int lj = j >> 1;
                bool upLane = ((lane & (k >> 1)) == 0);
                bool lowLane = ((lane & lj) == 0);
                bool keepMin = (upLane == lowLane);
#pragma unroll
                for (int r = 0; r < 2; ++r) {
                    double o = __shfl_xor(v[r], lj);
                    double mn = fmin(v[r], o), mx = fmax(v[r], o);
                    v[r] = keepMin ? mn : mx;
                }
            } else {
                bool up = (((lane * 2) & k) == 0);
                double mn = fmin(v[0], v[1]), mx = fmax(v[0], v[1]);
                v[0] = up ? mn : mx;
                v[1] = up ? mx : mn;
            }
        }
    }
}

__global__ __launch_bounds__(256) void knn_kernel(const float4* __restrict__ pos4,
                                                  int* __restrict__ idxout)
{
    int tid = threadIdx.x, lane = tid & 63, wv = tid >> 6;
    int p = blockIdx.x * 4 + wv;
    int b = p >> 11, n = p & 2047;
    __shared__ double cand[4][256];
    const float4* pb4 = pos4 + (size_t)b * 2048;
    float4 pn = pb4[n];
    float pn0 = pn.x, pn1 = pn.y, pn2 = pn.z, sqn = pn.w;
    double kd[32];
#pragma unroll
    for (int j = 0; j < 32; ++j) {
        int m = lane + j * 64;
        float4 qm = pb4[m];
        float dot = __fadd_rn(__fadd_rn(__fmul_rn(pn0, qm.x), __fmul_rn(pn1, qm.y)),
                              __fmul_rn(pn2, qm.z));
        float d2 = __fadd_rn(__fsub_rn(sqn, __fmul_rn(2.0f, dot)), qm.w);
        u32 u = __float_as_uint(d2);
        u = (u & 0x80000000u) ? ~u : (u | 0x80000000u);  // orderable
        u32 lo = (u << 11) | (u32)m;
        u32 hi = 0x43300000u | (u >> 21);
        kd[j] = __hiloint2double((int)hi, (int)lo);
    }

    // Phase 1: lane-minima (pairwise tree), 64-lane bitonic, T = 32nd smallest.
    double tmin[16];
#pragma unroll
    for (int j = 0; j < 16; ++j) tmin[j] = fmin(kd[j], kd[j + 16]);
#pragma unroll
    for (int j = 0; j < 8; ++j) tmin[j] = fmin(tmin[j], tmin[j + 8]);
#pragma unroll
    for (int j = 0; j < 4; ++j) tmin[j] = fmin(tmin[j], tmin[j + 4]);
    double lmin = fmin(fmin(tmin[0], tmin[2]), fmin(tmin[1], tmin[3]));
    double v = lmin;
#pragma unroll
    for (int k = 2; k <= 64; k <<= 1) {
#pragma unroll
        for (int j2 = k >> 1; j2 > 0; j2 >>= 1) {
            double o = __shfl_xor(v, j2);
            bool up = ((lane & k) == 0);
            bool low = ((lane & j2) == 0);
            double mn = fmin(v, o), mx = fmax(v, o);
            v = (up == low) ? mn : mx;
        }
    }
    double T = __shfl(v, 31);

    // Phase 2 (R10): per-lane count + prefix scan + per-lane compaction.
    int c = 0;
#pragma unroll
    for (int j = 0; j < 32; ++j) c += (kd[j] <= T) ? 1 : 0;
    int s = c;
#pragma unroll
    for (int off = 1; off < 64; off <<= 1) {
        int t = __shfl_up(s, off);
        if (lane >= off) s += t;
    }
    int base = __shfl(s, 63);
    int slot = s - c;  // exclusive prefix: this lane's first slot

#pragma unroll
    for (int s4 = 0; s4 < 4; ++s4) cand[wv][lane + s4 * 64] = 1e300;
    // wave-synchronous: pad stores precede compaction stores in instr order
#pragma unroll
    for (int j = 0; j < 32; ++j) {
        if (kd[j] <= T) {
            if (slot < 256) cand[wv][slot] = kd[j];
            ++slot;
        }
    }

    if (base <= 128) {   // base >= 32 guaranteed (32 lane-minima <= T)
        double kc[2];
#pragma unroll
        for (int j = 0; j < 2; ++j) kc[j] = cand[wv][lane * 2 + j];
        bitonic128(kc, lane);
        if (lane < 16) {
            int2 w;
            w.x = __double2loint(kc[0]) & 2047;
            w.y = __double2loint(kc[1]) & 2047;
            *(int2*)&idxout[(size_t)p * 32 + lane * 2] = w;
        }
    } else if (base <= 256) {
        double kc[4];
#pragma unroll
        for (int j = 0; j < 4; ++j) kc[j] = cand[wv][lane * 4 + j];
        bitonic256(kc, lane);
        if (lane < 8) {
            int4 w;
            w.x = __double2loint(kc[0]) & 2047;
            w.y = __double2loint(kc[1]) & 2047;
            w.z = __double2loint(kc[2]) & 2047;
            w.w = __double2loint(kc[3]) & 2047;
            *(int4*)&idxout[(size_t)p * 32 + lane * 4] = w;
        }
    } else {
        // Fallback: exact full-register selection (R9 path).
        double last = -1.0;
        for (int it = 0; it < 32; ++it) {
            double lm0 = 1e300, lm1 = 1e300;
#pragma unroll
            for (int j = 0; j < 32; j += 2) {
                double t0 = kd[j], t1 = kd[j + 1];
                lm0 = fmin(lm0, (t0 > last) ? t0 : 1e300);
                lm1 = fmin(lm1, (t1 > last) ? t1 : 1e300);
            }
            double lm = fmin(lm0, lm1);
#pragma unroll
            for (int off = 32; off; off >>= 1)
                lm = fmin(lm, __shfl_xor(lm, off));
            if (lane == 0) idxout[(size_t)p * 32 + it] = __double2loint(lm) & 2047;
            last = lm;
        }
    }
}

// ---------------------------------------------------------------------------
// UV GEMM: U[n][c] = x@(Wa1-Wa2)+ba  (f32, exact, read once per point);
//          V[n][c] = x@Wa2           (bf16, gathered 32x -> half traffic).
// A f32 -> split LDS, 3-term MFMA vs split weights (defines U/V precision).
// ---------------------------------------------------------------------------
template<int K, int KP, int N2>
__global__ __launch_bounds__(256) void uv_gemm(
    const float* __restrict__ xin, const u16* __restrict__ wT,
    const float* __restrict__ ba, float* __restrict__ Uf, u16* __restrict__ Vb)
{
    constexpr int SA = KP + 8;
    constexpr int WSZ = N2 * KP;
    constexpr int CMID = N2 / 2;
    __shared__ __align__(16) u16 AsH[32 * SA];
    __shared__ __align__(16) u16 AsL[32 * SA];
    int row0 = blockIdx.x * 32;
    int tid = threadIdx.x, lane = tid & 63, wv = tid >> 6, ln = lane & 15, q = lane >> 4;

    for (int e = tid; e < 32 * (KP / 8); e += 256) {
        int r = e / (KP / 8), c0 = (e % (KP / 8)) * 8;
        bf16x8 hv, lv;
#pragma unroll
        for (int jj = 0; jj < 8; ++jj) {
            int c = c0 + jj;
            float v = (c < K) ? xin[(size_t)(row0 + r) * K + c] : 0.f;
            u16 hi = f2b(v);
            hv[jj] = hi;
            lv[jj] = f2b(v - b2f(hi));
        }
        *(bf16x8*)&AsH[r * SA + c0] = hv;
        *(bf16x8*)&AsL[r * SA + c0] = lv;
    }
    __syncthreads();

    constexpr int NT = N2 / 64;
    f32x4 acc[2][NT] = {};
    const int wbase = wv * (N2 / 4);
#pragma unroll
    for (int ks = 0; ks < KP / 32; ++ks) {
        bf16x8 a0h = *(const bf16x8*)&AsH[(ln) * SA + ks * 32 + q * 8];
        bf16x8 a1h = *(const bf16x8*)&AsH[(16 + ln) * SA + ks * 32 + q * 8];
        bf16x8 a0l = *(const bf16x8*)&AsL[(ln) * SA + ks * 32 + q * 8];
        bf16x8 a1l = *(const bf16x8*)&AsL[(16 + ln) * SA + ks * 32 + q * 8];
#pragma unroll
        for (int nt = 0; nt < NT; ++nt) {
            size_t wi = (size_t)(wbase + nt * 16 + ln) * KP + ks * 32 + q * 8;
            bf16x8 bh = *(const bf16x8*)&wT[wi];
            bf16x8 bl = *(const bf16x8*)&wT[WSZ + wi];
            acc[0][nt] = mfma16(a0h, bh, acc[0][nt]);
            acc[0][nt] = mfma16(a0h, bl, acc[0][nt]);
            acc[0][nt] = mfma16(a0l, bh, acc[0][nt]);
            acc[1][nt] = mfma16(a1h, bh, acc[1][nt]);
            acc[1][nt] = mfma16(a1h, bl, acc[1][nt]);
            acc[1][nt] = mfma16(a1l, bh, acc[1][nt]);
        }
    }
#pragma unroll
    for (int nt = 0; nt < NT; ++nt) {
        int col = wbase + nt * 16 + ln;
#pragma unroll
        for (int mt = 0; mt < 2; ++mt)
#pragma unroll
            for (int r = 0; r < 4; ++r) {
                size_t row = (size_t)(row0 + mt * 16 + q * 4 + r);
                if (col < CMID)
                    Uf[row * CMID + col] = acc[mt][nt][r] + ba[col];
                else
                    Vb[row * CMID + (col - CMID)] = f2b(acc[mt][nt][r]);
            }
    }
}

// ---------------------------------------------------------------------------
// Edge pool — R2-PROVEN config (89.8us R10-measured on edge3; laws: (256,4),
// NTP<=2, 1-term Wb; edge3 PTS=2 locked — R3/R4 register-hoist REFUTED,
// allocator pins 64 VGPR). R1: ks unroll + 1-deep weight prefetch;
// conversion unroll. R9: XCD-aware chunked swizzle (one batch per XCD),
// FETCH 21.5 -> 7.7MB measured; bijective (nwg%8==0).
// R11: edge1 (KC=2, NTP=1) uses PTS=4 — live state acc[4][2][1]=32 VGPR +
// frags ~= 58 <= 64 law; halves block count for the tiniest blocks (8 MFMA/
// wave) to amortize fixed per-block cost. edge2/edge3 stay PTS=2 (acc would
// hit 64 VGPR alone at PTS=4).
// Tripwire: WRITE_SIZE ~= output, VGPR<=64, FETCH ~7.7MB on edge3.
// ---------------------------------------------------------------------------
template<int CMID, int COUT, bool OUTB, int PTS, int NTP>
__global__ __launch_bounds__(256, 4) void edge_pool(
    const float* __restrict__ Uf, const u16* __restrict__ Vb,
    const int* __restrict__ idx,
    const u16* __restrict__ wbT, const float* __restrict__ bb,
    void* __restrict__ outp)
{
    constexpr int KC = CMID / 32;
    constexpr int C8 = CMID / 8;
    constexpr int NTW = COUT / 64;
    constexpr int CITER = PTS * 32 * C8 / 256;  // exact (divisible)
    __shared__ __align__(16) u16 hfrag[PTS * 2 * KC * 512];
    __shared__ int nbr[PTS * 32];

    int tid = threadIdx.x, lane = tid & 63, wv = tid >> 6, ln = lane & 15, q = lane >> 4;
    int cpx = gridDim.x >> 3;
    int wgid = (blockIdx.x & 7) * cpx + (blockIdx.x >> 3);  // batch-per-XCD
    int p0 = wgid * PTS;

    if (tid < PTS * 32) {
        int pt = tid >> 5, kk = tid & 31;
        int p = p0 + pt;
        nbr[tid] = ((p >> 11) << 11) + (idx[(size_t)p * 32 + kk] & 2047);
    }
    __syncthreads();

    // build h in swizzled fragment order (packed conversion), unrolled so the
    // per-iteration gather/U loads issue back-to-back and pipeline
#pragma unroll
    for (int e0 = 0; e0 < CITER; ++e0) {
        int e = tid + e0 * 256;
        int pt = e / (32 * C8), rem = e % (32 * C8), r = rem / C8, c8 = rem % C8;
        const float* U = &Uf[(size_t)(p0 + pt) * CMID + c8 * 8];
        bf16x8 vb = *(const bf16x8*)&Vb[(size_t)nbr[pt * 32 + r] * CMID + c8 * 8];
        u32x4 hq;
#pragma unroll
        for (int jj = 0; jj < 4; ++jj) {
            float f0 = U[2 * jj]     + b2f((u16)vb[2 * jj]);
            float f1 = U[2 * jj + 1] + b2f((u16)vb[2 * jj + 1]);
            f0 = f0 >= 0.f ? f0 : 0.2f * f0;
            f1 = f1 >= 0.f ? f1 : 0.2f * f1;
            u32 a = __float_as_uint(f0) + 0x8000u;
            u32 b = __float_as_uint(f1) + 0x8000u;
            hq[jj] = __builtin_amdgcn_perm(b, a, 0x07060302u);  // hi16(f1)<<16|hi16(f0)
        }
        int mt = r >> 4, lnr = r & 15, ks = c8 >> 2, qq = c8 & 3;
        int slot = qq * 16 + (lnr ^ ((ks << 2) | qq));
        *(u32x4*)&hfrag[(((pt * 2 + mt) * KC + ks) * 64 + slot) * 8] = hq;
    }
    __syncthreads();

    for (int ng = 0; ng < NTW; ng += NTP) {
        f32x4 acc[PTS][2][NTP] = {};  // [pt][mt][nt]
        bf16x8 bh[NTP];
#pragma unroll
        for (int nt = 0; nt < NTP; ++nt) {
            size_t wi = ((size_t)((wv * NTW + ng + nt) * KC + 0) * 64 + lane) * 8;
            bh[nt] = *(const bf16x8*)&wbT[wi];
        }
#pragma unroll
        for (int ks = 0; ks < KC; ++ks) {
            bf16x8 bhn[NTP];
            if (ks + 1 < KC) {
#pragma unroll
                for (int nt = 0; nt < NTP; ++nt) {
                    size_t wi = ((size_t)((wv * NTW + ng + nt) * KC + (ks + 1)) * 64 + lane) * 8;
                    bhn[nt] = *(const bf16x8*)&wbT[wi];
                }
            }
            int slot = q * 16 + (ln ^ ((ks << 2) | q));
#pragma unroll
            for (int pt = 0; pt < PTS; ++pt)
#pragma unroll
                for (int mt = 0; mt < 2; ++mt) {
                    bf16x8 a = *(const bf16x8*)
                        &hfrag[(((pt * 2 + mt) * KC + ks) * 64 + slot) * 8];
#pragma unroll
                    for (int nt = 0; nt < NTP; ++nt)
                        acc[pt][mt][nt] = mfma16(a, bh[nt], acc[pt][mt][nt]);
                }
            if (ks + 1 < KC) {
#pragma unroll
                for (int nt = 0; nt < NTP; ++nt) bh[nt] = bhn[nt];
            }
        }
        // per-point max over 32 rows, bias+lrelu, store (frees accs)
#pragma unroll
        for (int pt = 0; pt < PTS; ++pt)
#pragma unroll
            for (int nt = 0; nt < NTP; ++nt) {
                int col = wv * (COUT / 4) + (ng + nt) * 16 + ln;
                float m = acc[pt][0][nt][0];
#pragma unroll
                for (int r = 1; r < 4; ++r) m = fmaxf(m, acc[pt][0][nt][r]);
#pragma unroll
                for (int r = 0; r < 4; ++r) m = fmaxf(m, acc[pt][1][nt][r]);
                m = fmaxf(m, __shfl_xor(m, 16));
                m = fmaxf(m, __shfl_xor(m, 32));
                if (q == 0) {
                    float v = m + bb[col];
                    v = v >= 0.f ? v : 0.2f * v;
                    if constexpr (OUTB)
                        ((u16*)outp)[(size_t)(p0 + pt) * COUT + col] = f2b(v);
                    else
                        ((float*)outp)[(size_t)(p0 + pt) * COUT + col] = v;
                }
            }
    }
}

// ---------------------------------------------------------------------------
// head123 (R7+R8 fusion): stage 1 = head1 (concat 704 -> 512, lrelu),
// bit-identical; 32x512 bf16 tile -> LDS Bs [32][520] (overlays AsH/AsL).
// Stage 2 = head_bf<512,256> body verbatim; its 32x256 bf16 output goes to
// LDS Bs2 [32][264] (overlays Bs after barrier) instead of HBM h2.
// Stage 3 = head_gemm3 body verbatim, wave 0 only (identical ks order and
// acc chains) -> final f32 out. Eliminates h1 (16MB W+R, R7) and h2
// (8MB W+R, R8) HBM round-trips + 2 launches. Output bit-identical.
// ---------------------------------------------------------------------------
__global__ __launch_bounds__(256) void head123(
    const float* __restrict__ x1, const float* __restrict__ x2,
    const u16* __restrict__ x3,
    const u16* __restrict__ wT1, const float* __restrict__ b1,
    const u16* __restrict__ wT2, const float* __restrict__ b2,
    const u16* __restrict__ wT3, const float* __restrict__ b3,
    float* __restrict__ out3)
{
    constexpr int KD = 704, KT = 352, SA = 360, SB = 520, SB3 = 264;
    __shared__ __align__(16) u16 lds[2 * 32 * SA];   // 46080 B
    u16* AsH = lds;
    u16* AsL = lds + 32 * SA;
    u16* Bs  = lds;                                  // stage-2 overlay [32][SB]
    u16* Bs2 = lds;                                  // stage-3 overlay [32][SB3]
    int row0 = blockIdx.x * 32;
    int tid = threadIdx.x, lane = tid & 63, wv = tid >> 6, ln = lane & 15, q = lane >> 4;

    f32x4 acc[2][8] = {};
    const int wbase = wv * 128;

    for (int ph = 0; ph < 2; ++ph) {
        if (ph) __syncthreads();
        for (int e = tid; e < 32 * 44; e += 256) {
            int r = e / 44, c8l = e % 44;
            int c = ph * KT + c8l * 8;
            int g = row0 + r;
            int a = r * SA + c8l * 8;
            if (c < 192) {
                const float* src = (c < 64) ? &x1[(size_t)g * 64 + c]
                                            : &x2[(size_t)g * 128 + (c - 64)];
                bf16x8 hv, lv;
#pragma unroll
                for (int jj = 0; jj < 8; ++jj) {
                    float v = src[jj];
                    u16 hi = f2b(v);
                    hv[jj] = hi;
                    lv[jj] = f2b(v - b2f(hi));
                }
                *(bf16x8*)&AsH[a] = hv;
                *(bf16x8*)&AsL[a] = lv;
            } else {
                *(bf16x8*)&AsH[a] = *(const bf16x8*)&x3[(size_t)g * 512 + (c - 192)];
                bf16x8 z = {0, 0, 0, 0, 0, 0, 0, 0};
                *(bf16x8*)&AsL[a] = z;
            }
        }
        __syncthreads();
        for (int ks = 0; ks < 11; ++ks) {
            int gk = ph * 11 + ks;
            bool t3 = (gk < 6);
            bf16x8 a0h = *(const bf16x8*)&AsH[(ln) * SA + ks * 32 + q * 8];
            bf16x8 a1h = *(const bf16x8*)&AsH[(16 + ln) * SA + ks * 32 + q * 8];
            bf16x8 a0l = *(const bf16x8*)&AsL[(ln) * SA + ks * 32 + q * 8];
            bf16x8 a1l = *(const bf16x8*)&AsL[(16 + ln) * SA + ks * 32 + q * 8];
#pragma unroll
            for (int nt = 0; nt < 8; ++nt) {
                size_t wi = (size_t)(wbase + nt * 16 + ln) * KD + gk * 32 + q * 8;
                bf16x8 bh = *(const bf16x8*)&wT1[wi];
                acc[0][nt] = mfma16(a0h, bh, acc[0][nt]);
                acc[1][nt] = mfma16(a1h, bh, acc[1][nt]);
                if (t3) {
                    acc[0][nt] = mfma16(a0l, bh, acc[0][nt]);
                    acc[1][nt] = mfma16(a1l, bh, acc[1][nt]);
                }
            }
        }
    }
    // stage-1 epilogue -> LDS exchange (bit-identical values to old h1)
    __syncthreads();   // all AsH/AsL reads done before overlay
#pragma unroll
    for (int nt = 0; nt < 8; ++nt) {
        int col = wbase + nt * 16 + ln;
        float bv = b1[col];
#pragma unroll
        for (int mt = 0; mt < 2; ++mt)
#pragma unroll
            for (int r = 0; r < 4; ++r) {
                float v = acc[mt][nt][r] + bv;
                v = v >= 0.f ? v : 0.2f * v;
                Bs[(mt * 16 + q * 4 + r) * SB + col] = f2b(v);
            }
    }
    __syncthreads();

    // stage 2: head_bf<512,256> body (verbatim indexing, SA -> SB)
    f32x4 acc2[2][4] = {};
    const int wbase2 = wv * 64;
    for (int ks = 0; ks < 16; ++ks) {
        bf16x8 a0 = *(const bf16x8*)&Bs[(ln) * SB + ks * 32 + q * 8];
        bf16x8 a1 = *(const bf16x8*)&Bs[(16 + ln) * SB + ks * 32 + q * 8];
#pragma unroll
        for (int nt = 0; nt < 4; ++nt) {
            size_t wi = (size_t)(wbase2 + nt * 16 + ln) * 512 + ks * 32 + q * 8;
            bf16x8 bh = *(const bf16x8*)&wT2[wi];
            acc2[0][nt] = mfma16(a0, bh, acc2[0][nt]);
            acc2[1][nt] = mfma16(a1, bh, acc2[1][nt]);
        }
    }
    // stage-2 epilogue -> LDS exchange Bs2 (bit-identical values to old h2)
    __syncthreads();   // all Bs reads done before overlay
#pragma unroll
    for (int nt = 0; nt < 4; ++nt) {
        int col = wbase2 + nt * 16 + ln;
        float bv = b2[col];
#pragma unroll
        for (int mt = 0; mt < 2; ++mt)
#pragma unroll
            for (int r = 0; r < 4; ++r) {
                float v = acc2[mt][nt][r] + bv;
                v = v >= 0.f ? v : 0.2f * v;
                Bs2[(mt * 16 + q * 4 + r) * SB3 + col] = f2b(v);
            }
    }
    __syncthreads();

    // stage 3: head_gemm3 body (verbatim ks order/acc chains), wave 0 only
    if (wv == 0) {
        f32x4 acc3[2] = {};
#pragma unroll
        for (int ks = 0; ks < 8; ++ks) {
            bf16x8 a0 = *(const bf16x8*)&Bs2[(ln) * SB3 + ks * 32 + q * 8];
            bf16x8 a1 = *(const bf16x8*)&Bs2[(16 + ln) * SB3 + ks * 32 + q * 8];
            size_t wi = (size_t)ln * 256 + ks * 32 + q * 8;
            bf16x8 bh = *(const bf16x8*)&wT3[wi];
            acc3[0] = mfma16(a0, bh, acc3[0]);
            acc3[1] = mfma16(a1, bh, acc3[1]);
        }
        if (ln < 12) {
            float bv = b3[ln];
#pragma unroll
            for (int mt = 0; mt < 2; ++mt)
#pragma unroll
                for (int r = 0; r < 4; ++r)
                    out3[(size_t)(row0 + mt * 16 + q * 4 + r) * 12 + ln] = acc3[mt][r] + bv;
        }
    }
}

// ---------------------------------------------------------------------------
// Workspace (peak 50,708,480 B = 48.4 MB):
//   [0,        2473984)  split weights
//   [2473984,  4571136)  idxb
//   [4571136,  8765440)  x1 f32      (pos4 256KB overlays head during
//                        prep+knn; x1 written after knn -> safe)
//   [8765440, 17154048)  x2 f32
//   [17154048,33931264)  Uf f32 (<=8MB) @ +0, Vb bf16 (<=4MB) @ +8MB
//   [33931264,50708480)  x3 bf16
// ---------------------------------------------------------------------------
extern "C" void kernel_launch(void* const* d_in, const int* in_sizes, int n_in,
                              void* d_out, int out_size, void* d_ws, size_t ws_size,
                              hipStream_t stream)
{
    (void)in_sizes; (void)n_in; (void)out_size; (void)ws_size;
    const float* x   = (const float*)d_in[0];
    const float* pos = (const float*)d_in[1];
    const float* w1a = (const float*)d_in[2];  const float* b1a = (const float*)d_in[3];
    const float* w1b = (const float*)d_in[4];  const float* b1b = (const float*)d_in[5];
    const float* w2a = (const float*)d_in[6];  const float* b2a = (const float*)d_in[7];
    const float* w2b = (const float*)d_in[8];  const float* b2b = (const float*)d_in[9];
    const float* w3a = (const float*)d_in[10]; const float* b3a = (const float*)d_in[11];
    const float* w3b = (const float*)d_in[12]; const float* b3b = (const float*)d_in[13];
    const float* wf1 = (const float*)d_in[14]; const float* bf1 = (const float*)d_in[15];
    const float* wf2 = (const float*)d_in[16]; const float* bf2 = (const float*)d_in[17];
    const float* wf3 = (const float*)d_in[18]; const float* bf3 = (const float*)d_in[19];

    char* ws = (char*)d_ws;
    u16* t1uv = (u16*)(ws + 0);
    u16* t2uv = (u16*)(ws + 16384);
    u16* t3uv = (u16*)(ws + 49152);
    u16* t1b  = (u16*)(ws + 180224);
    u16* t2b  = (u16*)(ws + 196608);
    u16* t3b  = (u16*)(ws + 229376);
    u16* tf1  = (u16*)(ws + 491520);
    u16* tf2  = (u16*)(ws + 1933312);
    u16* tf3  = (u16*)(ws + 2457600);
    int*   idxb = (int*)(ws + 2473984);
    float* x1 = (float*)(ws + 4571136);
    float* x2 = (float*)(ws + 8765440);
    float* Uf = (float*)(ws + 17154048);           // <= 8 MB (edge3)
    u16*   Vb = (u16*)(ws + 17154048 + 8388608);   // <= 4 MB (edge3)
    u16*   x3 = (u16*)(ws + 33931264);
    float4* pos4 = (float4*)(ws + 4571136);  // 256KB, dead after knn (x1 overlays)

    prep_weights<<<2480, 256, 0, stream>>>(w1a, w1b, w2a, w2b, w3a, w3b, wf1, wf2, wf3,
                                           pos, t1uv, t2uv, t3uv, t1b, t2b, t3b,
                                           tf1, tf2, tf3, pos4);
    knn_kernel<<<4096, 256, 0, stream>>>(pos4, idxb);
    uv_gemm<  3, 32, 128><<<512, 256, 0, stream>>>(x,  t1uv, b1a, Uf, Vb);
    edge_pool< 64,  64, false, 4, 1><<<4096, 256, 0, stream>>>(Uf, Vb, idxb, t1b, b1b, x1);
    uv_gemm< 64, 64, 128><<<512, 256, 0, stream>>>(x1, t2uv, b2a, Uf, Vb);
    edge_pool< 64, 128, false, 2, 2><<<8192, 256, 0, stream>>>(Uf, Vb, idxb, t2b, b2b, x2);
    uv_gemm<128, 128, 256><<<512, 256, 0, stream>>>(x2, t3uv, b3a, Uf, Vb);
    edge_pool<128, 512, true, 2, 2><<<8192, 256, 0, stream>>>(Uf, Vb, idxb, t3b, b3b, x3);
    head123<<<512, 256, 0, stream>>>(x1, x2, x3, tf1, bf1, tf2, bf2, tf3, bf3,
                                     (float*)d_out);
}